// Round 1
// baseline (4301.805 us; speedup 1.0000x reference)
//
#include <hip/hip_runtime.h>
#include <hip/hip_bf16.h>
#include <math.h>

// ---------------------------------------------------------------------------
// ViT forward, fp32 correctness-first implementation.
// B=128, C=3, 224x224, P=14 (16x16 patches), IN_D=768, D=256, H=8, DH=32,
// L=4, OUT=1000, S=197.
// ---------------------------------------------------------------------------

#define SEQ 197
#define DIM 256
#define NB  128
#define MROWS (NB * SEQ)        // 25216
#define PATCH_ROWS (NB * 196)   // 25088

// ---------------------------------------------------------------------------
// Positional encoding table: pe[s*256 + j]
__global__ __launch_bounds__(256) void pe_kernel(float* __restrict__ pe) {
    int s = blockIdx.x;           // 0..196
    int j = threadIdx.x;          // 0..255
    int jh = j >> 1;
    // 10000^(-(2*jh)/256) = exp2(-(2*jh)/256 * log2(10000))
    float expo = (float)(2 * jh) * (1.0f / 256.0f);
    float inv_freq = exp2f(-expo * 13.287712379549449f); // log2(10000)
    float angle = (float)s * inv_freq;
    pe[s * 256 + j] = (j & 1) ? cosf(angle) : sinf(angle);
}

// ---------------------------------------------------------------------------
// cls token row: out[n, 0, :] = cls_tok + pe[0]
__global__ __launch_bounds__(256) void embed_cls(const float* __restrict__ cls_tok,
                                                 const float* __restrict__ pe,
                                                 float* __restrict__ out) {
    int n = blockIdx.x, d = threadIdx.x;
    out[(size_t)n * SEQ * DIM + d] = cls_tok[d] + pe[d];
}

// ---------------------------------------------------------------------------
// Patch embedding GEMM: tokens[row, d] = sum_k patches[row,k] * w_map[d,k]
// row = n*196 + p; writes out[n, 1+p, d] += b_map + pe.
// M = 25088 (392 blocks of 64), N = 256 (4 blocks), K = 768.
__global__ __launch_bounds__(256) void patch_gemm(const float* __restrict__ images,
                                                  const float* __restrict__ w_map,
                                                  const float* __restrict__ b_map,
                                                  const float* __restrict__ pe,
                                                  float* __restrict__ out) {
    __shared__ float As[16][64];
    __shared__ float Bs[16][64];
    const int tid = threadIdx.x;
    const int bm = blockIdx.x * 64;
    const int bn = blockIdx.y * 64;
    const int tx = tid & 15, ty = tid >> 4;
    float acc[4][4] = {};

    for (int k0 = 0; k0 < 768; k0 += 16) {
#pragma unroll
        for (int u = 0; u < 4; ++u) {
            int e = tid + u * 256;
            int r = e >> 4, kk = e & 15;
            int row = bm + r;
            int n = row / 196, p = row % 196;
            int py = p / 14, px = p % 14;
            int kg = k0 + kk;
            int c = kg >> 8, rem = kg & 255;
            int a = rem >> 4, b = rem & 15;
            As[kk][r] = images[(((size_t)n * 3 + c) * 224 + py * 16 + a) * 224 + px * 16 + b];
            Bs[kk][r] = w_map[(size_t)(bn + r) * 768 + kg];
        }
        __syncthreads();
#pragma unroll
        for (int kk = 0; kk < 16; ++kk) {
            float4 av = *reinterpret_cast<const float4*>(&As[kk][ty * 4]);
            float4 bv = *reinterpret_cast<const float4*>(&Bs[kk][tx * 4]);
            float a[4] = {av.x, av.y, av.z, av.w};
            float b[4] = {bv.x, bv.y, bv.z, bv.w};
#pragma unroll
            for (int i = 0; i < 4; ++i)
#pragma unroll
                for (int j = 0; j < 4; ++j) acc[i][j] += a[i] * b[j];
        }
        __syncthreads();
    }
#pragma unroll
    for (int i = 0; i < 4; ++i) {
        int row = bm + ty * 4 + i;
        int n = row / 196, p = row % 196;
#pragma unroll
        for (int j = 0; j < 4; ++j) {
            int col = bn + tx * 4 + j;
            out[((size_t)n * SEQ + 1 + p) * DIM + col] =
                acc[i][j] + b_map[col] + pe[(1 + p) * DIM + col];
        }
    }
}

// ---------------------------------------------------------------------------
// Generic GEMM: C[M,N] (=|+=) act(A[M,K] * B[N,K]^T + bias[N])
// M % 64 == 0, N % 64 == 0, K % 16 == 0.
template <int ACT, bool ACCUM>
__global__ __launch_bounds__(256) void gemm_bt(const float* __restrict__ A,
                                               const float* __restrict__ B,
                                               const float* __restrict__ bias,
                                               float* __restrict__ C,
                                               int M, int N, int K) {
    __shared__ float As[16][64];
    __shared__ float Bs[16][64];
    const int tid = threadIdx.x;
    const int bm = blockIdx.x * 64;
    const int bn = blockIdx.y * 64;
    const int tx = tid & 15, ty = tid >> 4;
    float acc[4][4] = {};

    for (int k0 = 0; k0 < K; k0 += 16) {
#pragma unroll
        for (int u = 0; u < 4; ++u) {
            int e = tid + u * 256;
            int r = e >> 4, kk = e & 15;
            As[kk][r] = A[(size_t)(bm + r) * K + k0 + kk];
            Bs[kk][r] = B[(size_t)(bn + r) * K + k0 + kk];
        }
        __syncthreads();
#pragma unroll
        for (int kk = 0; kk < 16; ++kk) {
            float4 av = *reinterpret_cast<const float4*>(&As[kk][ty * 4]);
            float4 bv = *reinterpret_cast<const float4*>(&Bs[kk][tx * 4]);
            float a[4] = {av.x, av.y, av.z, av.w};
            float b[4] = {bv.x, bv.y, bv.z, bv.w};
#pragma unroll
            for (int i = 0; i < 4; ++i)
#pragma unroll
                for (int j = 0; j < 4; ++j) acc[i][j] += a[i] * b[j];
        }
        __syncthreads();
    }
#pragma unroll
    for (int i = 0; i < 4; ++i) {
        int row = bm + ty * 4 + i;
#pragma unroll
        for (int j = 0; j < 4; ++j) {
            int col = bn + tx * 4 + j;
            float v = acc[i][j] + bias[col];
            if (ACT == 1) v = 0.5f * v * (1.0f + erff(v * 0.70710678118654752f));
            size_t off = (size_t)row * N + col;
            if (ACCUM) C[off] += v; else C[off] = v;
        }
    }
}

// ---------------------------------------------------------------------------
// LayerNorm over last dim (256). One block per row.
__global__ __launch_bounds__(256) void ln_kernel(const float* __restrict__ x,
                                                 float* __restrict__ y,
                                                 const float* __restrict__ g,
                                                 const float* __restrict__ b) {
    int row = blockIdx.x, tid = threadIdx.x;
    float v = x[(size_t)row * DIM + tid];
    float s = v;
#pragma unroll
    for (int off = 32; off; off >>= 1) s += __shfl_down(s, off, 64);
    __shared__ float red[4];
    if ((tid & 63) == 0) red[tid >> 6] = s;
    __syncthreads();
    float mu = (red[0] + red[1] + red[2] + red[3]) * (1.0f / 256.0f);
    float d = v - mu;
    float s2 = d * d;
#pragma unroll
    for (int off = 32; off; off >>= 1) s2 += __shfl_down(s2, off, 64);
    __shared__ float red2[4];
    if ((tid & 63) == 0) red2[tid >> 6] = s2;
    __syncthreads();
    float var = (red2[0] + red2[1] + red2[2] + red2[3]) * (1.0f / 256.0f);
    float inv_std = 1.0f / sqrtf(var + 1e-5f);
    y[(size_t)row * DIM + tid] = d * inv_std * g[tid] + b[tid];
}

// ---------------------------------------------------------------------------
// QKV projection. Block handles 32 rows; per-head 32x32 weights in LDS.
__global__ __launch_bounds__(256) void qkv_kernel(const float* __restrict__ x,
                                                  const float* __restrict__ wq,
                                                  const float* __restrict__ bq,
                                                  const float* __restrict__ wk,
                                                  const float* __restrict__ bk,
                                                  const float* __restrict__ wv,
                                                  const float* __restrict__ bv,
                                                  float* __restrict__ q,
                                                  float* __restrict__ k,
                                                  float* __restrict__ v) {
    __shared__ float xs[32][256];
    __shared__ float ws[8][32][33];
    const int tid = threadIdx.x;
    const int rowbase = blockIdx.x * 32;
    for (int e = tid; e < 32 * 256; e += 256) {
        int r = e >> 8, d = e & 255;
        xs[r][d] = x[(size_t)(rowbase + r) * DIM + d];
    }
    const int h = tid >> 5, ei = tid & 31;
    const float* wptr[3] = {wq, wk, wv};
    const float* bptr[3] = {bq, bk, bv};
    float* optr[3] = {q, k, v};
#pragma unroll
    for (int m = 0; m < 3; ++m) {
        __syncthreads();
        for (int e = tid; e < 8192; e += 256) {
            int hh = e >> 10, rr = (e >> 5) & 31, dd = e & 31;
            ws[hh][rr][dd] = wptr[m][e];
        }
        __syncthreads();
        float bb = bptr[m][tid];
        for (int r = 0; r < 32; ++r) {
            float acc = bb;
#pragma unroll
            for (int dd = 0; dd < 32; ++dd) acc += xs[r][h * 32 + dd] * ws[h][ei][dd];
            optr[m][(size_t)(rowbase + r) * DIM + tid] = acc;
        }
    }
}

// ---------------------------------------------------------------------------
// Attention: one block per (n, h). K/V staged in LDS; thread s owns a row,
// online softmax, fp32.
__global__ __launch_bounds__(256) void attn_kernel(const float* __restrict__ q,
                                                   const float* __restrict__ k,
                                                   const float* __restrict__ v,
                                                   float* __restrict__ o) {
    __shared__ float ks[SEQ][32];
    __shared__ float vs[SEQ][32];
    const int n = blockIdx.x >> 3;
    const int h = blockIdx.x & 7;
    const int tid = threadIdx.x;
    for (int e = tid; e < SEQ * 32; e += 256) {
        int t = e >> 5, d = e & 31;
        size_t off = ((size_t)(n * SEQ + t)) * DIM + h * 32 + d;
        ks[t][d] = k[off];
        vs[t][d] = v[off];
    }
    __syncthreads();
    if (tid < SEQ) {
        const int s = tid;
        float qr[32], ov[32];
        size_t qoff = ((size_t)(n * SEQ + s)) * DIM + h * 32;
#pragma unroll
        for (int d = 0; d < 32; ++d) { qr[d] = q[qoff + d]; ov[d] = 0.f; }
        float m = -1e30f, lsum = 0.f;
        const float scale = 0.17677669529663687f; // 1/sqrt(32)
        for (int t = 0; t < SEQ; ++t) {
            float dot = 0.f;
#pragma unroll
            for (int d = 0; d < 32; ++d) dot += qr[d] * ks[t][d];
            dot *= scale;
            float mnew = fmaxf(m, dot);
            float corr = expf(m - mnew);
            float p = expf(dot - mnew);
            lsum = lsum * corr + p;
#pragma unroll
            for (int d = 0; d < 32; ++d) ov[d] = ov[d] * corr + p * vs[t][d];
            m = mnew;
        }
        float inv = 1.0f / lsum;
#pragma unroll
        for (int d = 0; d < 32; ++d) o[qoff + d] = ov[d] * inv;
    }
}

// ---------------------------------------------------------------------------
// Classifier head + softmax. One block per batch row.
__global__ __launch_bounds__(256) void head_kernel(const float* __restrict__ xin,
                                                   const float* __restrict__ w,
                                                   const float* __restrict__ bias,
                                                   float* __restrict__ res) {
    int n = blockIdx.x, tid = threadIdx.x;
    __shared__ float xs[256];
    xs[tid] = xin[(size_t)n * SEQ * DIM + tid];
    __syncthreads();
    float lg[4];
#pragma unroll
    for (int u = 0; u < 4; ++u) {
        int j = u * 256 + tid;
        float acc = -1e30f;
        if (j < 1000) {
            acc = bias[j];
            for (int kk = 0; kk < 256; kk += 4) {
                float4 wv = *reinterpret_cast<const float4*>(&w[(size_t)j * 256 + kk]);
                acc += xs[kk] * wv.x + xs[kk + 1] * wv.y + xs[kk + 2] * wv.z + xs[kk + 3] * wv.w;
            }
        }
        lg[u] = acc;
    }
    float mx = fmaxf(fmaxf(lg[0], lg[1]), fmaxf(lg[2], lg[3]));
#pragma unroll
    for (int off = 32; off; off >>= 1) mx = fmaxf(mx, __shfl_down(mx, off, 64));
    __shared__ float redm[4];
    if ((tid & 63) == 0) redm[tid >> 6] = mx;
    __syncthreads();
    mx = fmaxf(fmaxf(redm[0], redm[1]), fmaxf(redm[2], redm[3]));
    float e[4], ssum = 0.f;
#pragma unroll
    for (int u = 0; u < 4; ++u) {
        int j = u * 256 + tid;
        e[u] = (j < 1000) ? expf(lg[u] - mx) : 0.f;
        ssum += e[u];
    }
#pragma unroll
    for (int off = 32; off; off >>= 1) ssum += __shfl_down(ssum, off, 64);
    __shared__ float reds[4];
    if ((tid & 63) == 0) reds[tid >> 6] = ssum;
    __syncthreads();
    float inv = 1.0f / (reds[0] + reds[1] + reds[2] + reds[3]);
#pragma unroll
    for (int u = 0; u < 4; ++u) {
        int j = u * 256 + tid;
        if (j < 1000) res[(size_t)n * 1000 + j] = e[u] * inv;
    }
}

// ---------------------------------------------------------------------------
extern "C" void kernel_launch(void* const* d_in, const int* in_sizes, int n_in,
                              void* d_out, int out_size, void* d_ws, size_t ws_size,
                              hipStream_t stream) {
    const float* images  = (const float*)d_in[0];
    const float* w_map   = (const float*)d_in[1];
    const float* b_map   = (const float*)d_in[2];
    const float* cls_tok = (const float*)d_in[3];
    const float* norm1_g = (const float*)d_in[4];
    const float* norm1_b = (const float*)d_in[5];
    const float* wq      = (const float*)d_in[6];
    const float* bq      = (const float*)d_in[7];
    const float* wk      = (const float*)d_in[8];
    const float* bk      = (const float*)d_in[9];
    const float* wv      = (const float*)d_in[10];
    const float* bv      = (const float*)d_in[11];
    const float* w_last  = (const float*)d_in[12];
    const float* b_last  = (const float*)d_in[13];
    const float* norm2_g = (const float*)d_in[14];
    const float* norm2_b = (const float*)d_in[15];
    const float* w_mlp1  = (const float*)d_in[16];
    const float* b_mlp1  = (const float*)d_in[17];
    const float* w_mlp2  = (const float*)d_in[18];
    const float* b_mlp2  = (const float*)d_in[19];
    const float* w_out   = (const float*)d_in[20];
    const float* b_out   = (const float*)d_in[21];

    float* wsf = (float*)d_ws;
    const size_t SZ = (size_t)MROWS * DIM;   // 6,455,296 floats
    float* outb = wsf;            // residual stream
    float* xbuf = wsf + SZ;       // layernorm output
    float* qb   = wsf + 2 * SZ;
    float* kb   = wsf + 3 * SZ;
    float* vb   = wsf + 4 * SZ;
    float* ob   = wsf + 5 * SZ;
    float* h1   = qb;             // (M,1024) overlaps q..o exactly
    float* peb  = wsf + 6 * SZ;   // 197*256 floats

    pe_kernel<<<SEQ, 256, 0, stream>>>(peb);
    embed_cls<<<NB, 256, 0, stream>>>(cls_tok, peb, outb);
    patch_gemm<<<dim3(392, 4), 256, 0, stream>>>(images, w_map, b_map, peb, outb);

    for (int l = 0; l < 4; ++l) {
        ln_kernel<<<MROWS, 256, 0, stream>>>(outb, xbuf, norm1_g + l * 256, norm1_b + l * 256);
        qkv_kernel<<<MROWS / 32, 256, 0, stream>>>(xbuf,
            wq + (size_t)l * 8192, bq + l * 256,
            wk + (size_t)l * 8192, bk + l * 256,
            wv + (size_t)l * 8192, bv + l * 256, qb, kb, vb);
        attn_kernel<<<NB * 8, 256, 0, stream>>>(qb, kb, vb, ob);
        gemm_bt<0, true><<<dim3(MROWS / 64, 4), 256, 0, stream>>>(
            ob, w_last + (size_t)l * 65536, b_last + l * 256, outb, MROWS, 256, 256);
        ln_kernel<<<MROWS, 256, 0, stream>>>(outb, xbuf, norm2_g + l * 256, norm2_b + l * 256);
        gemm_bt<1, false><<<dim3(MROWS / 64, 16), 256, 0, stream>>>(
            xbuf, w_mlp1 + (size_t)l * 262144, b_mlp1 + l * 1024, h1, MROWS, 1024, 256);
        gemm_bt<0, true><<<dim3(MROWS / 64, 4), 256, 0, stream>>>(
            h1, w_mlp2 + (size_t)l * 262144, b_mlp2 + l * 256, outb, MROWS, 256, 1024);
    }
    head_kernel<<<NB, 256, 0, stream>>>(outb, w_out, b_out, (float*)d_out);
}

// Round 2
// 1974.820 us; speedup vs baseline: 2.1783x; 2.1783x over previous
//
#include <hip/hip_runtime.h>
#include <hip/hip_bf16.h>
#include <math.h>

// ---------------------------------------------------------------------------
// ViT forward. Round 1: split-bf16 MFMA GEMMs (hi/lo, 3 mfma per pair).
// B=128, C=3, 224x224, P=14, IN_D=768, D=256, H=8, DH=32, L=4, OUT=1000, S=197
// ---------------------------------------------------------------------------

#define SEQ 197
#define DIM 256
#define NB  128
#define MROWS (NB * SEQ)        // 25216 = 197*128
#define PATCH_ROWS (NB * 196)   // 25088 = 196*128

typedef __attribute__((ext_vector_type(4))) float f32x4;
typedef __attribute__((ext_vector_type(8))) __bf16 bf16x8;
typedef __attribute__((ext_vector_type(8))) short s16x8;

// round-to-nearest-even fp32 -> bf16 bits
__device__ __forceinline__ unsigned bf16_rn(float x) {
    union { float f; unsigned u; } c; c.f = x;
    return (c.u + 0x7fffu + ((c.u >> 16) & 1u)) >> 16;
}
__device__ __forceinline__ void split2(float a, unsigned short& hi, unsigned short& lo) {
    unsigned h = bf16_rn(a);
    hi = (unsigned short)h;
    union { unsigned u; float f; } hf; hf.u = h << 16;
    lo = (unsigned short)bf16_rn(a - hf.f);
}
// swizzled element offset in a [128 rows][32 k] ushort LDS tile (16B chunks XORed)
__device__ __forceinline__ int swz(int row, int c) {
    return row * 32 + ((c ^ ((row >> 1) & 3)) << 3);
}

// ---------------------------------------------------------------------------
__global__ __launch_bounds__(256) void pe_kernel(float* __restrict__ pe) {
    int s = blockIdx.x, j = threadIdx.x;
    int jh = j >> 1;
    float expo = (float)(2 * jh) * (1.0f / 256.0f);
    float inv_freq = exp2f(-expo * 13.287712379549449f);
    float angle = (float)s * inv_freq;
    pe[s * 256 + j] = (j & 1) ? cosf(angle) : sinf(angle);
}

__global__ __launch_bounds__(256) void embed_cls(const float* __restrict__ cls_tok,
                                                 const float* __restrict__ pe,
                                                 float* __restrict__ out) {
    int n = blockIdx.x, d = threadIdx.x;
    out[(size_t)n * SEQ * DIM + d] = cls_tok[d] + pe[d];
}

// split fp32 weights into hi/lo bf16 copies
__global__ __launch_bounds__(256) void split_weights(const float* __restrict__ src,
                                                     unsigned short* __restrict__ hi,
                                                     unsigned short* __restrict__ lo, int n) {
    for (int i = blockIdx.x * 256 + threadIdx.x; i < n; i += gridDim.x * 256) {
        unsigned short h, l;
        split2(src[i], h, l);
        hi[i] = h; lo[i] = l;
    }
}

// ---------------------------------------------------------------------------
// Split-bf16 MFMA GEMM: C[M,N] (=|+=) act(A[M,K] * B[N,K]^T + bias[N])
// Block 128x128, BK=32, 4 waves each computing 64x64.
template <int ACT, bool ACCUM>
__global__ __launch_bounds__(256) void gemm_mfma(const float* __restrict__ A,
                                                 const unsigned short* __restrict__ Bhi,
                                                 const unsigned short* __restrict__ Blo,
                                                 const float* __restrict__ bias,
                                                 float* __restrict__ C,
                                                 int M, int N, int K) {
    __shared__ unsigned short Ah[4096], Al[4096], Bh[4096], Bl[4096];
    const int tid = threadIdx.x;
    const int bm = blockIdx.x * 128, bn = blockIdx.y * 128;
    const int lane = tid & 63, wid = tid >> 6;
    const int wm = wid & 1, wn = wid >> 1;
    const int q = lane >> 4, r15 = lane & 15;
    const int srow = tid >> 2, sc = tid & 3;

    const float* aptr0 = A + (size_t)(bm + srow) * K + sc * 8;
    const float* aptr1 = A + (size_t)(bm + srow + 64) * K + sc * 8;
    const unsigned short* bh0 = Bhi + (size_t)(bn + srow) * K + sc * 8;
    const unsigned short* bl0 = Blo + (size_t)(bn + srow) * K + sc * 8;
    const unsigned short* bh1 = Bhi + (size_t)(bn + srow + 64) * K + sc * 8;
    const unsigned short* bl1 = Blo + (size_t)(bn + srow + 64) * K + sc * 8;
    const int soff0 = swz(srow, sc), soff1 = swz(srow + 64, sc);

    f32x4 acc[4][4];
#pragma unroll
    for (int i = 0; i < 4; ++i)
#pragma unroll
        for (int j = 0; j < 4; ++j) acc[i][j] = (f32x4){0.f, 0.f, 0.f, 0.f};

    for (int k0 = 0; k0 < K; k0 += 32) {
        {   // stage A (fp32 -> hi/lo bf16)
            float4 v0 = *(const float4*)(aptr0 + k0);
            float4 v1 = *(const float4*)(aptr0 + k0 + 4);
            float vv[8] = {v0.x, v0.y, v0.z, v0.w, v1.x, v1.y, v1.z, v1.w};
            s16x8 hv, lv;
#pragma unroll
            for (int j = 0; j < 8; ++j) {
                unsigned short h, l; split2(vv[j], h, l);
                hv[j] = (short)h; lv[j] = (short)l;
            }
            *(s16x8*)&Ah[soff0] = hv; *(s16x8*)&Al[soff0] = lv;
            v0 = *(const float4*)(aptr1 + k0);
            v1 = *(const float4*)(aptr1 + k0 + 4);
            float ww[8] = {v0.x, v0.y, v0.z, v0.w, v1.x, v1.y, v1.z, v1.w};
#pragma unroll
            for (int j = 0; j < 8; ++j) {
                unsigned short h, l; split2(ww[j], h, l);
                hv[j] = (short)h; lv[j] = (short)l;
            }
            *(s16x8*)&Ah[soff1] = hv; *(s16x8*)&Al[soff1] = lv;
        }
        // stage B (already bf16 hi/lo in global)
        *(s16x8*)&Bh[soff0] = *(const s16x8*)(bh0 + k0);
        *(s16x8*)&Bl[soff0] = *(const s16x8*)(bl0 + k0);
        *(s16x8*)&Bh[soff1] = *(const s16x8*)(bh1 + k0);
        *(s16x8*)&Bl[soff1] = *(const s16x8*)(bl1 + k0);
        __syncthreads();

        s16x8 ah[4], al[4], bhf[4], blf[4];
#pragma unroll
        for (int m = 0; m < 4; ++m) {
            int row = wm * 64 + m * 16 + r15;
            int off = row * 32 + ((q ^ ((row >> 1) & 3)) << 3);
            ah[m] = *(const s16x8*)&Ah[off];
            al[m] = *(const s16x8*)&Al[off];
        }
#pragma unroll
        for (int n = 0; n < 4; ++n) {
            int row = wn * 64 + n * 16 + r15;
            int off = row * 32 + ((q ^ ((row >> 1) & 3)) << 3);
            bhf[n] = *(const s16x8*)&Bh[off];
            blf[n] = *(const s16x8*)&Bl[off];
        }
#pragma unroll
        for (int m = 0; m < 4; ++m)
#pragma unroll
            for (int n = 0; n < 4; ++n) {
                bf16x8 a_h = __builtin_bit_cast(bf16x8, ah[m]);
                bf16x8 a_l = __builtin_bit_cast(bf16x8, al[m]);
                bf16x8 b_h = __builtin_bit_cast(bf16x8, bhf[n]);
                bf16x8 b_l = __builtin_bit_cast(bf16x8, blf[n]);
                acc[m][n] = __builtin_amdgcn_mfma_f32_16x16x32_bf16(a_h, b_h, acc[m][n], 0, 0, 0);
                acc[m][n] = __builtin_amdgcn_mfma_f32_16x16x32_bf16(a_h, b_l, acc[m][n], 0, 0, 0);
                acc[m][n] = __builtin_amdgcn_mfma_f32_16x16x32_bf16(a_l, b_h, acc[m][n], 0, 0, 0);
            }
        __syncthreads();
    }

#pragma unroll
    for (int n = 0; n < 4; ++n) {
        int col = bn + wn * 64 + n * 16 + r15;
        float bb = bias[col];
#pragma unroll
        for (int m = 0; m < 4; ++m) {
            int row0 = bm + wm * 64 + m * 16 + q * 4;
#pragma unroll
            for (int i = 0; i < 4; ++i) {
                float v = acc[m][n][i] + bb;
                if (ACT == 1) v = 0.5f * v * (1.0f + erff(v * 0.70710678118654752f));
                size_t off = (size_t)(row0 + i) * N + col;
                if (ACCUM) C[off] += v; else C[off] = v;
            }
        }
    }
}

// ---------------------------------------------------------------------------
// Patch-embed GEMM, MFMA version. A gathered from images, M=25088, N=256, K=768.
__global__ __launch_bounds__(256) void patch_mfma(const float* __restrict__ images,
                                                  const unsigned short* __restrict__ Bhi,
                                                  const unsigned short* __restrict__ Blo,
                                                  const float* __restrict__ b_map,
                                                  const float* __restrict__ pe,
                                                  float* __restrict__ out) {
    __shared__ unsigned short Ah[4096], Al[4096], Bh[4096], Bl[4096];
    const int tid = threadIdx.x;
    const int bm = blockIdx.x * 128, bn = blockIdx.y * 128;
    const int lane = tid & 63, wid = tid >> 6;
    const int wm = wid & 1, wn = wid >> 1;
    const int q = lane >> 4, r15 = lane & 15;
    const int srow = tid >> 2, sc = tid & 3;

    const float* ibase[2];
    {
        int rows[2] = {bm + srow, bm + srow + 64};
#pragma unroll
        for (int t = 0; t < 2; ++t) {
            int n = rows[t] / 196, p = rows[t] % 196;
            ibase[t] = images + (size_t)n * 150528 + (size_t)(p / 14) * 3584 + (p % 14) * 16;
        }
    }
    const int soff0 = swz(srow, sc), soff1 = swz(srow + 64, sc);
    const unsigned short* bh0 = Bhi + (size_t)(bn + srow) * 768 + sc * 8;
    const unsigned short* bl0 = Blo + (size_t)(bn + srow) * 768 + sc * 8;
    const unsigned short* bh1 = Bhi + (size_t)(bn + srow + 64) * 768 + sc * 8;
    const unsigned short* bl1 = Blo + (size_t)(bn + srow + 64) * 768 + sc * 8;

    f32x4 acc[4][4];
#pragma unroll
    for (int i = 0; i < 4; ++i)
#pragma unroll
        for (int j = 0; j < 4; ++j) acc[i][j] = (f32x4){0.f, 0.f, 0.f, 0.f};

    for (int k0 = 0; k0 < 768; k0 += 32) {
        int k = k0 + sc * 8;
        int aoff = (k >> 8) * 50176 + (((k >> 4) & 15)) * 224 + (k & 15);
        {
            float4 v0 = *(const float4*)(ibase[0] + aoff);
            float4 v1 = *(const float4*)(ibase[0] + aoff + 4);
            float vv[8] = {v0.x, v0.y, v0.z, v0.w, v1.x, v1.y, v1.z, v1.w};
            s16x8 hv, lv;
#pragma unroll
            for (int j = 0; j < 8; ++j) {
                unsigned short h, l; split2(vv[j], h, l);
                hv[j] = (short)h; lv[j] = (short)l;
            }
            *(s16x8*)&Ah[soff0] = hv; *(s16x8*)&Al[soff0] = lv;
            v0 = *(const float4*)(ibase[1] + aoff);
            v1 = *(const float4*)(ibase[1] + aoff + 4);
            float ww[8] = {v0.x, v0.y, v0.z, v0.w, v1.x, v1.y, v1.z, v1.w};
#pragma unroll
            for (int j = 0; j < 8; ++j) {
                unsigned short h, l; split2(ww[j], h, l);
                hv[j] = (short)h; lv[j] = (short)l;
            }
            *(s16x8*)&Ah[soff1] = hv; *(s16x8*)&Al[soff1] = lv;
        }
        *(s16x8*)&Bh[soff0] = *(const s16x8*)(bh0 + k0);
        *(s16x8*)&Bl[soff0] = *(const s16x8*)(bl0 + k0);
        *(s16x8*)&Bh[soff1] = *(const s16x8*)(bh1 + k0);
        *(s16x8*)&Bl[soff1] = *(const s16x8*)(bl1 + k0);
        __syncthreads();

        s16x8 ah[4], al[4], bhf[4], blf[4];
#pragma unroll
        for (int m = 0; m < 4; ++m) {
            int row = wm * 64 + m * 16 + r15;
            int off = row * 32 + ((q ^ ((row >> 1) & 3)) << 3);
            ah[m] = *(const s16x8*)&Ah[off];
            al[m] = *(const s16x8*)&Al[off];
        }
#pragma unroll
        for (int n = 0; n < 4; ++n) {
            int row = wn * 64 + n * 16 + r15;
            int off = row * 32 + ((q ^ ((row >> 1) & 3)) << 3);
            bhf[n] = *(const s16x8*)&Bh[off];
            blf[n] = *(const s16x8*)&Bl[off];
        }
#pragma unroll
        for (int m = 0; m < 4; ++m)
#pragma unroll
            for (int n = 0; n < 4; ++n) {
                bf16x8 a_h = __builtin_bit_cast(bf16x8, ah[m]);
                bf16x8 a_l = __builtin_bit_cast(bf16x8, al[m]);
                bf16x8 b_h = __builtin_bit_cast(bf16x8, bhf[n]);
                bf16x8 b_l = __builtin_bit_cast(bf16x8, blf[n]);
                acc[m][n] = __builtin_amdgcn_mfma_f32_16x16x32_bf16(a_h, b_h, acc[m][n], 0, 0, 0);
                acc[m][n] = __builtin_amdgcn_mfma_f32_16x16x32_bf16(a_h, b_l, acc[m][n], 0, 0, 0);
                acc[m][n] = __builtin_amdgcn_mfma_f32_16x16x32_bf16(a_l, b_h, acc[m][n], 0, 0, 0);
            }
        __syncthreads();
    }

#pragma unroll
    for (int n = 0; n < 4; ++n) {
        int col = bn + wn * 64 + n * 16 + r15;
        float bb = b_map[col];
#pragma unroll
        for (int m = 0; m < 4; ++m) {
            int row0 = bm + wm * 64 + m * 16 + q * 4;
#pragma unroll
            for (int i = 0; i < 4; ++i) {
                int rowg = row0 + i;
                int n_img = rowg / 196;
                int p = rowg - n_img * 196;
                out[((size_t)n_img * SEQ + 1 + p) * DIM + col] =
                    acc[m][n][i] + bb + pe[(1 + p) * DIM + col];
            }
        }
    }
}

// ---------------------------------------------------------------------------
__global__ __launch_bounds__(256) void ln_kernel(const float* __restrict__ x,
                                                 float* __restrict__ y,
                                                 const float* __restrict__ g,
                                                 const float* __restrict__ b) {
    int row = blockIdx.x, tid = threadIdx.x;
    float v = x[(size_t)row * DIM + tid];
    float s = v;
#pragma unroll
    for (int off = 32; off; off >>= 1) s += __shfl_down(s, off, 64);
    __shared__ float red[4];
    if ((tid & 63) == 0) red[tid >> 6] = s;
    __syncthreads();
    float mu = (red[0] + red[1] + red[2] + red[3]) * (1.0f / 256.0f);
    float d = v - mu;
    float s2 = d * d;
#pragma unroll
    for (int off = 32; off; off >>= 1) s2 += __shfl_down(s2, off, 64);
    __shared__ float red2[4];
    if ((tid & 63) == 0) red2[tid >> 6] = s2;
    __syncthreads();
    float var = (red2[0] + red2[1] + red2[2] + red2[3]) * (1.0f / 256.0f);
    float inv_std = 1.0f / sqrtf(var + 1e-5f);
    y[(size_t)row * DIM + tid] = d * inv_std * g[tid] + b[tid];
}

// ---------------------------------------------------------------------------
__global__ __launch_bounds__(256) void qkv_kernel(const float* __restrict__ x,
                                                  const float* __restrict__ wq,
                                                  const float* __restrict__ bq,
                                                  const float* __restrict__ wk,
                                                  const float* __restrict__ bk,
                                                  const float* __restrict__ wv,
                                                  const float* __restrict__ bv,
                                                  float* __restrict__ q,
                                                  float* __restrict__ k,
                                                  float* __restrict__ v) {
    __shared__ float xs[32][256];
    __shared__ float ws[8][32][33];
    const int tid = threadIdx.x;
    const int rowbase = blockIdx.x * 32;
    for (int e = tid; e < 32 * 256; e += 256) {
        int r = e >> 8, d = e & 255;
        xs[r][d] = x[(size_t)(rowbase + r) * DIM + d];
    }
    const int h = tid >> 5, ei = tid & 31;
    const float* wptr[3] = {wq, wk, wv};
    const float* bptr[3] = {bq, bk, bv};
    float* optr[3] = {q, k, v};
#pragma unroll
    for (int m = 0; m < 3; ++m) {
        __syncthreads();
        for (int e = tid; e < 8192; e += 256) {
            int hh = e >> 10, rr = (e >> 5) & 31, dd = e & 31;
            ws[hh][rr][dd] = wptr[m][e];
        }
        __syncthreads();
        float bb = bptr[m][tid];
        for (int r = 0; r < 32; ++r) {
            float acc = bb;
#pragma unroll
            for (int dd = 0; dd < 32; ++dd) acc += xs[r][h * 32 + dd] * ws[h][ei][dd];
            optr[m][(size_t)(rowbase + r) * DIM + tid] = acc;
        }
    }
}

// ---------------------------------------------------------------------------
__global__ __launch_bounds__(256) void attn_kernel(const float* __restrict__ q,
                                                   const float* __restrict__ k,
                                                   const float* __restrict__ v,
                                                   float* __restrict__ o) {
    __shared__ float ks[SEQ][32];
    __shared__ float vs[SEQ][32];
    const int n = blockIdx.x >> 3;
    const int h = blockIdx.x & 7;
    const int tid = threadIdx.x;
    for (int e = tid; e < SEQ * 32; e += 256) {
        int t = e >> 5, d = e & 31;
        size_t off = ((size_t)(n * SEQ + t)) * DIM + h * 32 + d;
        ks[t][d] = k[off];
        vs[t][d] = v[off];
    }
    __syncthreads();
    if (tid < SEQ) {
        const int s = tid;
        float qr[32], ov[32];
        size_t qoff = ((size_t)(n * SEQ + s)) * DIM + h * 32;
#pragma unroll
        for (int d = 0; d < 32; ++d) { qr[d] = q[qoff + d]; ov[d] = 0.f; }
        float m = -1e30f, lsum = 0.f;
        const float scale = 0.17677669529663687f;
        for (int t = 0; t < SEQ; ++t) {
            float dot = 0.f;
#pragma unroll
            for (int d = 0; d < 32; ++d) dot += qr[d] * ks[t][d];
            dot *= scale;
            float mnew = fmaxf(m, dot);
            float corr = expf(m - mnew);
            float p = expf(dot - mnew);
            lsum = lsum * corr + p;
#pragma unroll
            for (int d = 0; d < 32; ++d) ov[d] = ov[d] * corr + p * vs[t][d];
            m = mnew;
        }
        float inv = 1.0f / lsum;
#pragma unroll
        for (int d = 0; d < 32; ++d) o[qoff + d] = ov[d] * inv;
    }
}

// ---------------------------------------------------------------------------
__global__ __launch_bounds__(256) void head_kernel(const float* __restrict__ xin,
                                                   const float* __restrict__ w,
                                                   const float* __restrict__ bias,
                                                   float* __restrict__ res) {
    int n = blockIdx.x, tid = threadIdx.x;
    __shared__ float xs[256];
    xs[tid] = xin[(size_t)n * SEQ * DIM + tid];
    __syncthreads();
    float lg[4];
#pragma unroll
    for (int u = 0; u < 4; ++u) {
        int j = u * 256 + tid;
        float acc = -1e30f;
        if (j < 1000) {
            acc = bias[j];
            for (int kk = 0; kk < 256; kk += 4) {
                float4 wv = *reinterpret_cast<const float4*>(&w[(size_t)j * 256 + kk]);
                acc += xs[kk] * wv.x + xs[kk + 1] * wv.y + xs[kk + 2] * wv.z + xs[kk + 3] * wv.w;
            }
        }
        lg[u] = acc;
    }
    float mx = fmaxf(fmaxf(lg[0], lg[1]), fmaxf(lg[2], lg[3]));
#pragma unroll
    for (int off = 32; off; off >>= 1) mx = fmaxf(mx, __shfl_down(mx, off, 64));
    __shared__ float redm[4];
    if ((tid & 63) == 0) redm[tid >> 6] = mx;
    __syncthreads();
    mx = fmaxf(fmaxf(redm[0], redm[1]), fmaxf(redm[2], redm[3]));
    float e[4], ssum = 0.f;
#pragma unroll
    for (int u = 0; u < 4; ++u) {
        int j = u * 256 + tid;
        e[u] = (j < 1000) ? expf(lg[u] - mx) : 0.f;
        ssum += e[u];
    }
#pragma unroll
    for (int off = 32; off; off >>= 1) ssum += __shfl_down(ssum, off, 64);
    __shared__ float reds[4];
    if ((tid & 63) == 0) reds[tid >> 6] = ssum;
    __syncthreads();
    float inv = 1.0f / (reds[0] + reds[1] + reds[2] + reds[3]);
#pragma unroll
    for (int u = 0; u < 4; ++u) {
        int j = u * 256 + tid;
        if (j < 1000) res[(size_t)n * 1000 + j] = e[u] * inv;
    }
}

// ---------------------------------------------------------------------------
extern "C" void kernel_launch(void* const* d_in, const int* in_sizes, int n_in,
                              void* d_out, int out_size, void* d_ws, size_t ws_size,
                              hipStream_t stream) {
    const float* images  = (const float*)d_in[0];
    const float* w_map   = (const float*)d_in[1];
    const float* b_map   = (const float*)d_in[2];
    const float* cls_tok = (const float*)d_in[3];
    const float* norm1_g = (const float*)d_in[4];
    const float* norm1_b = (const float*)d_in[5];
    const float* wq      = (const float*)d_in[6];
    const float* bq      = (const float*)d_in[7];
    const float* wk      = (const float*)d_in[8];
    const float* bk      = (const float*)d_in[9];
    const float* wv      = (const float*)d_in[10];
    const float* bv      = (const float*)d_in[11];
    const float* w_last  = (const float*)d_in[12];
    const float* b_last  = (const float*)d_in[13];
    const float* norm2_g = (const float*)d_in[14];
    const float* norm2_b = (const float*)d_in[15];
    const float* w_mlp1  = (const float*)d_in[16];
    const float* b_mlp1  = (const float*)d_in[17];
    const float* w_mlp2  = (const float*)d_in[18];
    const float* b_mlp2  = (const float*)d_in[19];
    const float* w_out   = (const float*)d_in[20];
    const float* b_out   = (const float*)d_in[21];

    float* wsf = (float*)d_ws;
    const size_t SZ = (size_t)MROWS * DIM;   // 6,455,296 floats
    float* outb = wsf;
    float* xbuf = wsf + SZ;
    float* qb   = wsf + 2 * SZ;
    float* kb   = wsf + 3 * SZ;
    float* vb   = wsf + 4 * SZ;
    float* ob   = wsf + 5 * SZ;
    float* h1   = qb;                        // (M,1024) overlaps q..o exactly
    float* peb  = wsf + 6 * SZ;              // 50432 floats

    // split-weight buffers (bf16 hi/lo), after pe (padded to 65536 floats)
    const size_t W_MAP  = 0;                 // 196608
    const size_t W_LAST = 196608;            // 4 * 65536
    const size_t W_MLP1 = 458752;            // 4 * 262144
    const size_t W_MLP2 = 1507328;           // 4 * 262144
    const size_t W_TOTAL = 2555904;
    unsigned short* whi = (unsigned short*)(wsf + 6 * SZ + 65536);
    unsigned short* wlo = whi + W_TOTAL;

    pe_kernel<<<SEQ, 256, 0, stream>>>(peb);
    split_weights<<<768, 256, 0, stream>>>(w_map,  whi + W_MAP,  wlo + W_MAP,  196608);
    split_weights<<<1024, 256, 0, stream>>>(w_last, whi + W_LAST, wlo + W_LAST, 262144);
    split_weights<<<2048, 256, 0, stream>>>(w_mlp1, whi + W_MLP1, wlo + W_MLP1, 1048576);
    split_weights<<<2048, 256, 0, stream>>>(w_mlp2, whi + W_MLP2, wlo + W_MLP2, 1048576);

    embed_cls<<<NB, 256, 0, stream>>>(cls_tok, peb, outb);
    patch_mfma<<<dim3(196, 2), 256, 0, stream>>>(images, whi + W_MAP, wlo + W_MAP,
                                                 b_map, peb, outb);

    for (int l = 0; l < 4; ++l) {
        ln_kernel<<<MROWS, 256, 0, stream>>>(outb, xbuf, norm1_g + l * 256, norm1_b + l * 256);
        qkv_kernel<<<MROWS / 32, 256, 0, stream>>>(xbuf,
            wq + (size_t)l * 8192, bq + l * 256,
            wk + (size_t)l * 8192, bk + l * 256,
            wv + (size_t)l * 8192, bv + l * 256, qb, kb, vb);
        attn_kernel<<<NB * 8, 256, 0, stream>>>(qb, kb, vb, ob);
        gemm_mfma<0, true><<<dim3(197, 2), 256, 0, stream>>>(
            ob, whi + W_LAST + (size_t)l * 65536, wlo + W_LAST + (size_t)l * 65536,
            b_last + l * 256, outb, MROWS, 256, 256);
        ln_kernel<<<MROWS, 256, 0, stream>>>(outb, xbuf, norm2_g + l * 256, norm2_b + l * 256);
        gemm_mfma<1, false><<<dim3(197, 8), 256, 0, stream>>>(
            xbuf, whi + W_MLP1 + (size_t)l * 262144, wlo + W_MLP1 + (size_t)l * 262144,
            b_mlp1 + l * 1024, h1, MROWS, 1024, 256);
        gemm_mfma<0, true><<<dim3(197, 2), 256, 0, stream>>>(
            h1, whi + W_MLP2 + (size_t)l * 262144, wlo + W_MLP2 + (size_t)l * 262144,
            b_mlp2 + l * 256, outb, MROWS, 256, 1024);
    }
    head_kernel<<<NB, 256, 0, stream>>>(outb, w_out, b_out, (float*)d_out);
}

// Round 4
// 1442.159 us; speedup vs baseline: 2.9829x; 1.3693x over previous
//
#include <hip/hip_runtime.h>
#include <hip/hip_bf16.h>
#include <math.h>

// ---------------------------------------------------------------------------
// ViT forward. Round 3: R2 design with workspace shrunk below proven 157.75MiB
// (compact block-diagonal QKV weights) + hardened MFMA attention.
// B=128, C=3, 224x224, P=14, IN_D=768, D=256, H=8, DH=32, L=4, OUT=1000, S=197
// ---------------------------------------------------------------------------

#define SEQ 197
#define DIM 256
#define NB  128
#define MROWS (NB * SEQ)        // 25216 = 197*128

typedef __attribute__((ext_vector_type(4))) float f32x4;
typedef __attribute__((ext_vector_type(8))) __bf16 bf16x8;
typedef __attribute__((ext_vector_type(8))) short s16x8;

// round-to-nearest-even fp32 -> bf16 bits
__device__ __forceinline__ unsigned bf16_rn(float x) {
    union { float f; unsigned u; } c; c.f = x;
    return (c.u + 0x7fffu + ((c.u >> 16) & 1u)) >> 16;
}
__device__ __forceinline__ void split2(float a, unsigned short& hi, unsigned short& lo) {
    unsigned h = bf16_rn(a);
    hi = (unsigned short)h;
    union { unsigned u; float f; } hf; hf.u = h << 16;
    lo = (unsigned short)bf16_rn(a - hf.f);
}
// swizzled element offset in a [128 rows][32 k] ushort LDS tile (16B chunks XORed)
__device__ __forceinline__ int swz(int row, int c) {
    return row * 32 + ((c ^ ((row >> 1) & 3)) << 3);
}

// ---------------------------------------------------------------------------
__global__ __launch_bounds__(256) void pe_kernel(float* __restrict__ pe) {
    int s = blockIdx.x, j = threadIdx.x;
    int jh = j >> 1;
    float expo = (float)(2 * jh) * (1.0f / 256.0f);
    float inv_freq = exp2f(-expo * 13.287712379549449f);
    float angle = (float)s * inv_freq;
    pe[s * 256 + j] = (j & 1) ? cosf(angle) : sinf(angle);
}

__global__ __launch_bounds__(256) void embed_cls(const float* __restrict__ cls_tok,
                                                 const float* __restrict__ pe,
                                                 float* __restrict__ out) {
    int n = blockIdx.x, d = threadIdx.x;
    out[(size_t)n * SEQ * DIM + d] = cls_tok[d] + pe[d];
}

// split fp32 weights into hi/lo bf16 copies
__global__ __launch_bounds__(256) void split_weights(const float* __restrict__ src,
                                                     unsigned short* __restrict__ hi,
                                                     unsigned short* __restrict__ lo, int n) {
    for (int i = blockIdx.x * 256 + threadIdx.x; i < n; i += gridDim.x * 256) {
        unsigned short h, l;
        split2(src[i], h, l);
        hi[i] = h; lo[i] = l;
    }
}

// Compact QKV weights: wc[l][j][d] (j = m*256 + hh*32 + e, d = 0..31), hi bf16.
__global__ __launch_bounds__(256) void pack_qkv_c(const float* __restrict__ wq,
                                                  const float* __restrict__ wk,
                                                  const float* __restrict__ wv,
                                                  unsigned short* __restrict__ wc) {
    int e = blockIdx.x * 256 + threadIdx.x;     // < 4*768*32 = 98304
    if (e >= 98304) return;
    int l = e / 24576, r = e % 24576;
    int j = r >> 5, d = r & 31;
    int m = j >> 8, hh = (j >> 5) & 7, ee = j & 31;
    const float* w = (m == 0) ? wq : (m == 1) ? wk : wv;
    wc[e] = (unsigned short)bf16_rn(w[(((size_t)l * 8 + hh) * 32 + ee) * 32 + d]);
}

__global__ __launch_bounds__(256) void pack_qkv_b(const float* __restrict__ bq,
                                                  const float* __restrict__ bk,
                                                  const float* __restrict__ bv,
                                                  float* __restrict__ bp) {
    int e = blockIdx.x * 256 + threadIdx.x;     // < 4*768 = 3072
    if (e >= 3072) return;
    int l = e / 768, j = e % 768;
    int m = j >> 8, jj = j & 255;
    const float* b = (m == 0) ? bq : (m == 1) ? bk : bv;
    bp[e] = b[l * 256 + jj];
}

// ---------------------------------------------------------------------------
// Split-bf16 MFMA GEMM: C[M,N] (=|+=) act(A[M,K] * B[N,K]^T + bias[N])
// Block 128x128, BK=32, 4 waves each computing 64x64.
template <int ACT, bool ACCUM>
__global__ __launch_bounds__(256) void gemm_mfma(const float* __restrict__ A,
                                                 const unsigned short* __restrict__ Bhi,
                                                 const unsigned short* __restrict__ Blo,
                                                 const float* __restrict__ bias,
                                                 float* __restrict__ C,
                                                 int M, int N, int K) {
    __shared__ unsigned short Ah[4096], Al[4096], Bh[4096], Bl[4096];
    const int tid = threadIdx.x;
    const int bm = blockIdx.x * 128, bn = blockIdx.y * 128;
    const int lane = tid & 63, wid = tid >> 6;
    const int wm = wid & 1, wn = wid >> 1;
    const int q = lane >> 4, r15 = lane & 15;
    const int srow = tid >> 2, sc = tid & 3;

    const float* aptr0 = A + (size_t)(bm + srow) * K + sc * 8;
    const float* aptr1 = A + (size_t)(bm + srow + 64) * K + sc * 8;
    const unsigned short* bh0 = Bhi + (size_t)(bn + srow) * K + sc * 8;
    const unsigned short* bl0 = Blo + (size_t)(bn + srow) * K + sc * 8;
    const unsigned short* bh1 = Bhi + (size_t)(bn + srow + 64) * K + sc * 8;
    const unsigned short* bl1 = Blo + (size_t)(bn + srow + 64) * K + sc * 8;
    const int soff0 = swz(srow, sc), soff1 = swz(srow + 64, sc);

    f32x4 acc[4][4];
#pragma unroll
    for (int i = 0; i < 4; ++i)
#pragma unroll
        for (int j = 0; j < 4; ++j) acc[i][j] = (f32x4){0.f, 0.f, 0.f, 0.f};

    for (int k0 = 0; k0 < K; k0 += 32) {
        {   // stage A (fp32 -> hi/lo bf16)
            float4 v0 = *(const float4*)(aptr0 + k0);
            float4 v1 = *(const float4*)(aptr0 + k0 + 4);
            float vv[8] = {v0.x, v0.y, v0.z, v0.w, v1.x, v1.y, v1.z, v1.w};
            s16x8 hv, lv;
#pragma unroll
            for (int j = 0; j < 8; ++j) {
                unsigned short h, l; split2(vv[j], h, l);
                hv[j] = (short)h; lv[j] = (short)l;
            }
            *(s16x8*)&Ah[soff0] = hv; *(s16x8*)&Al[soff0] = lv;
            v0 = *(const float4*)(aptr1 + k0);
            v1 = *(const float4*)(aptr1 + k0 + 4);
            float ww[8] = {v0.x, v0.y, v0.z, v0.w, v1.x, v1.y, v1.z, v1.w};
#pragma unroll
            for (int j = 0; j < 8; ++j) {
                unsigned short h, l; split2(ww[j], h, l);
                hv[j] = (short)h; lv[j] = (short)l;
            }
            *(s16x8*)&Ah[soff1] = hv; *(s16x8*)&Al[soff1] = lv;
        }
        // stage B (already bf16 hi/lo in global)
        *(s16x8*)&Bh[soff0] = *(const s16x8*)(bh0 + k0);
        *(s16x8*)&Bl[soff0] = *(const s16x8*)(bl0 + k0);
        *(s16x8*)&Bh[soff1] = *(const s16x8*)(bh1 + k0);
        *(s16x8*)&Bl[soff1] = *(const s16x8*)(bl1 + k0);
        __syncthreads();

        s16x8 ah[4], al[4], bhf[4], blf[4];
#pragma unroll
        for (int m = 0; m < 4; ++m) {
            int row = wm * 64 + m * 16 + r15;
            int off = row * 32 + ((q ^ ((row >> 1) & 3)) << 3);
            ah[m] = *(const s16x8*)&Ah[off];
            al[m] = *(const s16x8*)&Al[off];
        }
#pragma unroll
        for (int n = 0; n < 4; ++n) {
            int row = wn * 64 + n * 16 + r15;
            int off = row * 32 + ((q ^ ((row >> 1) & 3)) << 3);
            bhf[n] = *(const s16x8*)&Bh[off];
            blf[n] = *(const s16x8*)&Bl[off];
        }
#pragma unroll
        for (int m = 0; m < 4; ++m)
#pragma unroll
            for (int n = 0; n < 4; ++n) {
                bf16x8 a_h = __builtin_bit_cast(bf16x8, ah[m]);
                bf16x8 a_l = __builtin_bit_cast(bf16x8, al[m]);
                bf16x8 b_h = __builtin_bit_cast(bf16x8, bhf[n]);
                bf16x8 b_l = __builtin_bit_cast(bf16x8, blf[n]);
                acc[m][n] = __builtin_amdgcn_mfma_f32_16x16x32_bf16(a_h, b_h, acc[m][n], 0, 0, 0);
                acc[m][n] = __builtin_amdgcn_mfma_f32_16x16x32_bf16(a_h, b_l, acc[m][n], 0, 0, 0);
                acc[m][n] = __builtin_amdgcn_mfma_f32_16x16x32_bf16(a_l, b_h, acc[m][n], 0, 0, 0);
            }
        __syncthreads();
    }

#pragma unroll
    for (int n = 0; n < 4; ++n) {
        int col = bn + wn * 64 + n * 16 + r15;
        float bb = bias[col];
#pragma unroll
        for (int m = 0; m < 4; ++m) {
            int row0 = bm + wm * 64 + m * 16 + q * 4;
#pragma unroll
            for (int i = 0; i < 4; ++i) {
                float v = acc[m][n][i] + bb;
                if (ACT == 1) v = 0.5f * v * (1.0f + erff(v * 0.70710678118654752f));
                size_t off = (size_t)(row0 + i) * N + col;
                if (ACCUM) C[off] += v; else C[off] = v;
            }
        }
    }
}

// ---------------------------------------------------------------------------
// QKV GEMM with COMPACT block-diagonal B: Bc[j][32] hi-bf16; row j's weights
// live in input k-chunk ((j>>5)&7). C[M,768] = A[M,256] * W^T + bias.
__global__ __launch_bounds__(256) void gemm_qkv(const float* __restrict__ A,
                                                const unsigned short* __restrict__ Bc,
                                                const float* __restrict__ bias,
                                                float* __restrict__ C,
                                                int M, int N, int K) {
    __shared__ unsigned short Ah[4096], Al[4096], Bh[4096];
    const int tid = threadIdx.x;
    const int bm = blockIdx.x * 128, bn = blockIdx.y * 128;
    const int lane = tid & 63, wid = tid >> 6;
    const int wm = wid & 1, wn = wid >> 1;
    const int q = lane >> 4, r15 = lane & 15;
    const int srow = tid >> 2, sc = tid & 3;

    const float* aptr0 = A + (size_t)(bm + srow) * K + sc * 8;
    const float* aptr1 = A + (size_t)(bm + srow + 64) * K + sc * 8;
    const int j0 = bn + srow, j1 = bn + srow + 64;
    const int c0 = (j0 >> 5) & 7, c1 = (j1 >> 5) & 7;
    const unsigned short* bc0 = Bc + (size_t)j0 * 32 + sc * 8;
    const unsigned short* bc1 = Bc + (size_t)j1 * 32 + sc * 8;
    const int soff0 = swz(srow, sc), soff1 = swz(srow + 64, sc);

    f32x4 acc[4][4];
#pragma unroll
    for (int i = 0; i < 4; ++i)
#pragma unroll
        for (int j = 0; j < 4; ++j) acc[i][j] = (f32x4){0.f, 0.f, 0.f, 0.f};

    const s16x8 bz = (s16x8){0, 0, 0, 0, 0, 0, 0, 0};
    for (int k0 = 0; k0 < K; k0 += 32) {
        const int kc = k0 >> 5;
        {   // stage A (fp32 -> hi/lo bf16)
            float4 v0 = *(const float4*)(aptr0 + k0);
            float4 v1 = *(const float4*)(aptr0 + k0 + 4);
            float vv[8] = {v0.x, v0.y, v0.z, v0.w, v1.x, v1.y, v1.z, v1.w};
            s16x8 hv, lv;
#pragma unroll
            for (int j = 0; j < 8; ++j) {
                unsigned short h, l; split2(vv[j], h, l);
                hv[j] = (short)h; lv[j] = (short)l;
            }
            *(s16x8*)&Ah[soff0] = hv; *(s16x8*)&Al[soff0] = lv;
            v0 = *(const float4*)(aptr1 + k0);
            v1 = *(const float4*)(aptr1 + k0 + 4);
            float ww[8] = {v0.x, v0.y, v0.z, v0.w, v1.x, v1.y, v1.z, v1.w};
#pragma unroll
            for (int j = 0; j < 8; ++j) {
                unsigned short h, l; split2(ww[j], h, l);
                hv[j] = (short)h; lv[j] = (short)l;
            }
            *(s16x8*)&Ah[soff1] = hv; *(s16x8*)&Al[soff1] = lv;
        }
        // stage B: compact row active only in its own k-chunk
        *(s16x8*)&Bh[soff0] = (c0 == kc) ? *(const s16x8*)bc0 : bz;
        *(s16x8*)&Bh[soff1] = (c1 == kc) ? *(const s16x8*)bc1 : bz;
        __syncthreads();

        s16x8 ah[4], al[4], bhf[4];
#pragma unroll
        for (int m = 0; m < 4; ++m) {
            int row = wm * 64 + m * 16 + r15;
            int off = row * 32 + ((q ^ ((row >> 1) & 3)) << 3);
            ah[m] = *(const s16x8*)&Ah[off];
            al[m] = *(const s16x8*)&Al[off];
        }
#pragma unroll
        for (int n = 0; n < 4; ++n) {
            int row = wn * 64 + n * 16 + r15;
            int off = row * 32 + ((q ^ ((row >> 1) & 3)) << 3);
            bhf[n] = *(const s16x8*)&Bh[off];
        }
#pragma unroll
        for (int m = 0; m < 4; ++m)
#pragma unroll
            for (int n = 0; n < 4; ++n) {
                bf16x8 a_h = __builtin_bit_cast(bf16x8, ah[m]);
                bf16x8 a_l = __builtin_bit_cast(bf16x8, al[m]);
                bf16x8 b_h = __builtin_bit_cast(bf16x8, bhf[n]);
                acc[m][n] = __builtin_amdgcn_mfma_f32_16x16x32_bf16(a_h, b_h, acc[m][n], 0, 0, 0);
                acc[m][n] = __builtin_amdgcn_mfma_f32_16x16x32_bf16(a_l, b_h, acc[m][n], 0, 0, 0);
            }
        __syncthreads();
    }

#pragma unroll
    for (int n = 0; n < 4; ++n) {
        int col = bn + wn * 64 + n * 16 + r15;
        float bb = bias[col];
#pragma unroll
        for (int m = 0; m < 4; ++m) {
            int row0 = bm + wm * 64 + m * 16 + q * 4;
#pragma unroll
            for (int i = 0; i < 4; ++i)
                C[(size_t)(row0 + i) * N + col] = acc[m][n][i] + bb;
        }
    }
}

// ---------------------------------------------------------------------------
// Patch-embed GEMM, MFMA version. A gathered from images, M=25088, N=256, K=768.
__global__ __launch_bounds__(256) void patch_mfma(const float* __restrict__ images,
                                                  const unsigned short* __restrict__ Bhi,
                                                  const unsigned short* __restrict__ Blo,
                                                  const float* __restrict__ b_map,
                                                  const float* __restrict__ pe,
                                                  float* __restrict__ out) {
    __shared__ unsigned short Ah[4096], Al[4096], Bh[4096], Bl[4096];
    const int tid = threadIdx.x;
    const int bm = blockIdx.x * 128, bn = blockIdx.y * 128;
    const int lane = tid & 63, wid = tid >> 6;
    const int wm = wid & 1, wn = wid >> 1;
    const int q = lane >> 4, r15 = lane & 15;
    const int srow = tid >> 2, sc = tid & 3;

    const float* ibase[2];
    {
        int rows[2] = {bm + srow, bm + srow + 64};
#pragma unroll
        for (int t = 0; t < 2; ++t) {
            int n = rows[t] / 196, p = rows[t] % 196;
            ibase[t] = images + (size_t)n * 150528 + (size_t)(p / 14) * 3584 + (p % 14) * 16;
        }
    }
    const int soff0 = swz(srow, sc), soff1 = swz(srow + 64, sc);
    const unsigned short* bh0 = Bhi + (size_t)(bn + srow) * 768 + sc * 8;
    const unsigned short* bl0 = Blo + (size_t)(bn + srow) * 768 + sc * 8;
    const unsigned short* bh1 = Bhi + (size_t)(bn + srow + 64) * 768 + sc * 8;
    const unsigned short* bl1 = Blo + (size_t)(bn + srow + 64) * 768 + sc * 8;

    f32x4 acc[4][4];
#pragma unroll
    for (int i = 0; i < 4; ++i)
#pragma unroll
        for (int j = 0; j < 4; ++j) acc[i][j] = (f32x4){0.f, 0.f, 0.f, 0.f};

    for (int k0 = 0; k0 < 768; k0 += 32) {
        int k = k0 + sc * 8;
        int aoff = (k >> 8) * 50176 + (((k >> 4) & 15)) * 224 + (k & 15);
        {
            float4 v0 = *(const float4*)(ibase[0] + aoff);
            float4 v1 = *(const float4*)(ibase[0] + aoff + 4);
            float vv[8] = {v0.x, v0.y, v0.z, v0.w, v1.x, v1.y, v1.z, v1.w};
            s16x8 hv, lv;
#pragma unroll
            for (int j = 0; j < 8; ++j) {
                unsigned short h, l; split2(vv[j], h, l);
                hv[j] = (short)h; lv[j] = (short)l;
            }
            *(s16x8*)&Ah[soff0] = hv; *(s16x8*)&Al[soff0] = lv;
            v0 = *(const float4*)(ibase[1] + aoff);
            v1 = *(const float4*)(ibase[1] + aoff + 4);
            float ww[8] = {v0.x, v0.y, v0.z, v0.w, v1.x, v1.y, v1.z, v1.w};
#pragma unroll
            for (int j = 0; j < 8; ++j) {
                unsigned short h, l; split2(ww[j], h, l);
                hv[j] = (short)h; lv[j] = (short)l;
            }
            *(s16x8*)&Ah[soff1] = hv; *(s16x8*)&Al[soff1] = lv;
        }
        *(s16x8*)&Bh[soff0] = *(const s16x8*)(bh0 + k0);
        *(s16x8*)&Bl[soff0] = *(const s16x8*)(bl0 + k0);
        *(s16x8*)&Bh[soff1] = *(const s16x8*)(bh1 + k0);
        *(s16x8*)&Bl[soff1] = *(const s16x8*)(bl1 + k0);
        __syncthreads();

        s16x8 ah[4], al[4], bhf[4], blf[4];
#pragma unroll
        for (int m = 0; m < 4; ++m) {
            int row = wm * 64 + m * 16 + r15;
            int off = row * 32 + ((q ^ ((row >> 1) & 3)) << 3);
            ah[m] = *(const s16x8*)&Ah[off];
            al[m] = *(const s16x8*)&Al[off];
        }
#pragma unroll
        for (int n = 0; n < 4; ++n) {
            int row = wn * 64 + n * 16 + r15;
            int off = row * 32 + ((q ^ ((row >> 1) & 3)) << 3);
            bhf[n] = *(const s16x8*)&Bh[off];
            blf[n] = *(const s16x8*)&Bl[off];
        }
#pragma unroll
        for (int m = 0; m < 4; ++m)
#pragma unroll
            for (int n = 0; n < 4; ++n) {
                bf16x8 a_h = __builtin_bit_cast(bf16x8, ah[m]);
                bf16x8 a_l = __builtin_bit_cast(bf16x8, al[m]);
                bf16x8 b_h = __builtin_bit_cast(bf16x8, bhf[n]);
                bf16x8 b_l = __builtin_bit_cast(bf16x8, blf[n]);
                acc[m][n] = __builtin_amdgcn_mfma_f32_16x16x32_bf16(a_h, b_h, acc[m][n], 0, 0, 0);
                acc[m][n] = __builtin_amdgcn_mfma_f32_16x16x32_bf16(a_h, b_l, acc[m][n], 0, 0, 0);
                acc[m][n] = __builtin_amdgcn_mfma_f32_16x16x32_bf16(a_l, b_h, acc[m][n], 0, 0, 0);
            }
        __syncthreads();
    }

#pragma unroll
    for (int n = 0; n < 4; ++n) {
        int col = bn + wn * 64 + n * 16 + r15;
        float bb = b_map[col];
#pragma unroll
        for (int m = 0; m < 4; ++m) {
            int row0 = bm + wm * 64 + m * 16 + q * 4;
#pragma unroll
            for (int i = 0; i < 4; ++i) {
                int rowg = row0 + i;
                int n_img = rowg / 196;
                int p = rowg - n_img * 196;
                out[((size_t)n_img * SEQ + 1 + p) * DIM + col] =
                    acc[m][n][i] + bb + pe[(1 + p) * DIM + col];
            }
        }
    }
}

// ---------------------------------------------------------------------------
// MFMA attention (hardened). One block per (n,h). 4 waves x 16-row q-strips.
__global__ __launch_bounds__(256) void attn_mfma(const float* __restrict__ qkv,
                                                 float* __restrict__ o) {
    __shared__ unsigned short Kh[208 * 40];      // K[s][d], rows >=197 zero
    __shared__ unsigned short Vt[32 * 232];      // V^T[d][t], cols >=197 zero
    __shared__ unsigned short Pb[4][16 * 232];   // per-wave P[qr][t]
    const int tid = threadIdx.x;
    const int lane = tid & 63, wid = tid >> 6;
    const int qh = lane >> 4, qr = lane & 15;
    const int n = blockIdx.x >> 3, h = blockIdx.x & 7;
    const size_t rowbase = (size_t)n * SEQ;
    const float scale = 0.17677669529663687f;    // 1/sqrt(32)

    // zero-init each LDS array separately (no layout assumptions)
    for (int i = tid; i < 208 * 40 / 2; i += 256) ((uint32_t*)Kh)[i] = 0;
    for (int i = tid; i < 32 * 232 / 2; i += 256) ((uint32_t*)Vt)[i] = 0;
    for (int i = tid; i < 4 * 16 * 232 / 2; i += 256) ((uint32_t*)&Pb[0][0])[i] = 0;
    __syncthreads();

    // stage K (hi bf16) and V^T (hi bf16)
    for (int e = tid; e < SEQ * 8; e += 256) {
        int s = e >> 3, c = e & 7;
        const float* base = qkv + (rowbase + s) * 768 + h * 32 + c * 4;
        float4 kv = *(const float4*)(base + 256);
        Kh[s * 40 + c * 4 + 0] = (unsigned short)bf16_rn(kv.x);
        Kh[s * 40 + c * 4 + 1] = (unsigned short)bf16_rn(kv.y);
        Kh[s * 40 + c * 4 + 2] = (unsigned short)bf16_rn(kv.z);
        Kh[s * 40 + c * 4 + 3] = (unsigned short)bf16_rn(kv.w);
        float4 vv = *(const float4*)(base + 512);
        Vt[(c * 4 + 0) * 232 + s] = (unsigned short)bf16_rn(vv.x);
        Vt[(c * 4 + 1) * 232 + s] = (unsigned short)bf16_rn(vv.y);
        Vt[(c * 4 + 2) * 232 + s] = (unsigned short)bf16_rn(vv.z);
        Vt[(c * 4 + 3) * 232 + s] = (unsigned short)bf16_rn(vv.w);
    }
    __syncthreads();

    unsigned short* Pw = Pb[wid];
    for (int st = wid; st < 13; st += 4) {
        // Q B-frag direct from global (scaled, split hi/lo)
        int srow = st * 16 + qr; if (srow > SEQ - 1) srow = SEQ - 1;
        const float* qp = qkv + (rowbase + srow) * 768 + h * 32 + qh * 8;
        float4 a = *(const float4*)qp, b = *(const float4*)(qp + 4);
        float qv[8] = {a.x, a.y, a.z, a.w, b.x, b.y, b.z, b.w};
        s16x8 qhi, qlo;
#pragma unroll
        for (int j = 0; j < 8; ++j) {
            unsigned short hh, ll; split2(qv[j] * scale, hh, ll);
            qhi[j] = (short)hh; qlo[j] = (short)ll;
        }
        bf16x8 qH = __builtin_bit_cast(bf16x8, qhi);
        bf16x8 qL = __builtin_bit_cast(bf16x8, qlo);

        // S^T: sacc[tt][i] = S[t = 16tt+4qh+i][qrow = st*16+qr]
        f32x4 sacc[13];
#pragma unroll
        for (int tt = 0; tt < 13; ++tt) sacc[tt] = (f32x4){0.f, 0.f, 0.f, 0.f};
#pragma unroll
        for (int tt = 0; tt < 13; ++tt) {
            bf16x8 kf = *(const bf16x8*)&Kh[(tt * 16 + qr) * 40 + qh * 8];
            sacc[tt] = __builtin_amdgcn_mfma_f32_16x16x32_bf16(kf, qH, sacc[tt], 0, 0, 0);
            sacc[tt] = __builtin_amdgcn_mfma_f32_16x16x32_bf16(kf, qL, sacc[tt], 0, 0, 0);
        }
        // mask invalid t (t = 192+4qh+i >= 197): -60 => exp contributes ~1e-26
#pragma unroll
        for (int i = 0; i < 4; ++i)
            if (192 + 4 * qh + i > SEQ - 1) sacc[12][i] = -60.0f;
        // row max over 52 values + 4-lane group reduce (lanes qr,+16,+32,+48)
        float mx = -60.0f;
#pragma unroll
        for (int tt = 0; tt < 13; ++tt)
#pragma unroll
            for (int i = 0; i < 4; ++i) mx = fmaxf(mx, sacc[tt][i]);
        mx = fmaxf(mx, __shfl_xor(mx, 16, 64));
        mx = fmaxf(mx, __shfl_xor(mx, 32, 64));
        float sum = 0.f;
#pragma unroll
        for (int tt = 0; tt < 13; ++tt)
#pragma unroll
            for (int i = 0; i < 4; ++i) {
                float p = __expf(sacc[tt][i] - mx);
                sacc[tt][i] = p; sum += p;
            }
        sum += __shfl_xor(sum, 16, 64);
        sum += __shfl_xor(sum, 32, 64);
        float inv = 1.0f / sum;
        // write unnormalized P (bf16) to wave-local LDS
#pragma unroll
        for (int tt = 0; tt < 13; ++tt)
#pragma unroll
            for (int i = 0; i < 4; ++i)
                Pw[qr * 232 + tt * 16 + 4 * qh + i] = (unsigned short)bf16_rn(sacc[tt][i]);
        // explicit zero of P tail cols 208..223 (read by last PV k-tile)
#pragma unroll
        for (int i = 0; i < 4; ++i)
            Pw[qr * 232 + 208 + 4 * qh + i] = 0;

        // O^T = V^T * P^T : oacc[dt][i] = O[qrow][d = 16dt+4qh+i]
        f32x4 oacc[2];
        oacc[0] = (f32x4){0.f, 0.f, 0.f, 0.f};
        oacc[1] = (f32x4){0.f, 0.f, 0.f, 0.f};
#pragma unroll
        for (int kt = 0; kt < 7; ++kt) {
            bf16x8 pf = *(const bf16x8*)&Pw[qr * 232 + kt * 32 + qh * 8];
            bf16x8 v0 = *(const bf16x8*)&Vt[qr * 232 + kt * 32 + qh * 8];
            bf16x8 v1 = *(const bf16x8*)&Vt[(16 + qr) * 232 + kt * 32 + qh * 8];
            oacc[0] = __builtin_amdgcn_mfma_f32_16x16x32_bf16(v0, pf, oacc[0], 0, 0, 0);
            oacc[1] = __builtin_amdgcn_mfma_f32_16x16x32_bf16(v1, pf, oacc[1], 0, 0, 0);
        }
        // write O (normalized)
        if (st * 16 + qr < SEQ) {
            float* op = o + (rowbase + st * 16 + qr) * DIM + h * 32;
#pragma unroll
            for (int dt = 0; dt < 2; ++dt)
#pragma unroll
                for (int i = 0; i < 4; ++i)
                    op[dt * 16 + 4 * qh + i] = oacc[dt][i] * inv;
        }
    }
}

// ---------------------------------------------------------------------------
__global__ __launch_bounds__(256) void ln_kernel(const float* __restrict__ x,
                                                 float* __restrict__ y,
                                                 const float* __restrict__ g,
                                                 const float* __restrict__ b) {
    int row = blockIdx.x, tid = threadIdx.x;
    float v = x[(size_t)row * DIM + tid];
    float s = v;
#pragma unroll
    for (int off = 32; off; off >>= 1) s += __shfl_down(s, off, 64);
    __shared__ float red[4];
    if ((tid & 63) == 0) red[tid >> 6] = s;
    __syncthreads();
    float mu = (red[0] + red[1] + red[2] + red[3]) * (1.0f / 256.0f);
    float d = v - mu;
    float s2 = d * d;
#pragma unroll
    for (int off = 32; off; off >>= 1) s2 += __shfl_down(s2, off, 64);
    __shared__ float red2[4];
    if ((tid & 63) == 0) red2[tid >> 6] = s2;
    __syncthreads();
    float var = (red2[0] + red2[1] + red2[2] + red2[3]) * (1.0f / 256.0f);
    float inv_std = 1.0f / sqrtf(var + 1e-5f);
    y[(size_t)row * DIM + tid] = d * inv_std * g[tid] + b[tid];
}

// ---------------------------------------------------------------------------
__global__ __launch_bounds__(256) void head_kernel(const float* __restrict__ xin,
                                                   const float* __restrict__ w,
                                                   const float* __restrict__ bias,
                                                   float* __restrict__ res) {
    int n = blockIdx.x, tid = threadIdx.x;
    __shared__ float xs[256];
    xs[tid] = xin[(size_t)n * SEQ * DIM + tid];
    __syncthreads();
    float lg[4];
#pragma unroll
    for (int u = 0; u < 4; ++u) {
        int j = u * 256 + tid;
        float acc = -1e30f;
        if (j < 1000) {
            acc = bias[j];
            for (int kk = 0; kk < 256; kk += 4) {
                float4 wv = *reinterpret_cast<const float4*>(&w[(size_t)j * 256 + kk]);
                acc += xs[kk] * wv.x + xs[kk + 1] * wv.y + xs[kk + 2] * wv.z + xs[kk + 3] * wv.w;
            }
        }
        lg[u] = acc;
    }
    float mx = fmaxf(fmaxf(lg[0], lg[1]), fmaxf(lg[2], lg[3]));
#pragma unroll
    for (int off = 32; off; off >>= 1) mx = fmaxf(mx, __shfl_down(mx, off, 64));
    __shared__ float redm[4];
    if ((tid & 63) == 0) redm[tid >> 6] = mx;
    __syncthreads();
    mx = fmaxf(fmaxf(redm[0], redm[1]), fmaxf(redm[2], redm[3]));
    float e[4], ssum = 0.f;
#pragma unroll
    for (int u = 0; u < 4; ++u) {
        int j = u * 256 + tid;
        e[u] = (j < 1000) ? expf(lg[u] - mx) : 0.f;
        ssum += e[u];
    }
#pragma unroll
    for (int off = 32; off; off >>= 1) ssum += __shfl_down(ssum, off, 64);
    __shared__ float reds[4];
    if ((tid & 63) == 0) reds[tid >> 6] = ssum;
    __syncthreads();
    float inv = 1.0f / (reds[0] + reds[1] + reds[2] + reds[3]);
#pragma unroll
    for (int u = 0; u < 4; ++u) {
        int j = u * 256 + tid;
        if (j < 1000) res[(size_t)n * 1000 + j] = e[u] * inv;
    }
}

// ---------------------------------------------------------------------------
extern "C" void kernel_launch(void* const* d_in, const int* in_sizes, int n_in,
                              void* d_out, int out_size, void* d_ws, size_t ws_size,
                              hipStream_t stream) {
    const float* images  = (const float*)d_in[0];
    const float* w_map   = (const float*)d_in[1];
    const float* b_map   = (const float*)d_in[2];
    const float* cls_tok = (const float*)d_in[3];
    const float* norm1_g = (const float*)d_in[4];
    const float* norm1_b = (const float*)d_in[5];
    const float* wq      = (const float*)d_in[6];
    const float* bq      = (const float*)d_in[7];
    const float* wk      = (const float*)d_in[8];
    const float* bk      = (const float*)d_in[9];
    const float* wv      = (const float*)d_in[10];
    const float* bv      = (const float*)d_in[11];
    const float* w_last  = (const float*)d_in[12];
    const float* b_last  = (const float*)d_in[13];
    const float* norm2_g = (const float*)d_in[14];
    const float* norm2_b = (const float*)d_in[15];
    const float* w_mlp1  = (const float*)d_in[16];
    const float* b_mlp1  = (const float*)d_in[17];
    const float* w_mlp2  = (const float*)d_in[18];
    const float* b_mlp2  = (const float*)d_in[19];
    const float* w_out   = (const float*)d_in[20];
    const float* b_out   = (const float*)d_in[21];

    float* wsf = (float*)d_ws;
    const size_t SZ = (size_t)MROWS * DIM;   // 6,455,296 floats
    float* outb = wsf;                       // residual stream [M,256]
    float* xbuf = wsf + SZ;                  // LN output [M,256]
    float* qkvb = wsf + 2 * SZ;              // [M,768]
    float* ob   = wsf + 5 * SZ;              // [M,256]
    float* h1   = wsf + 2 * SZ;              // [M,1024] overlaps qkvb+ob
    float* peb  = wsf + 6 * SZ;              // 50432 floats (exact)

    // Total ws usage: 165,561,344 B = 157.89 MiB (< R1's proven-fitting layout +150KB)
    const size_t W_MAP  = 0;                 // 196608
    const size_t W_LAST = 196608;            // 4 * 65536
    const size_t W_MLP1 = 458752;            // 4 * 262144
    const size_t W_MLP2 = 1507328;           // 4 * 262144
    const size_t W_TOTAL = 2555904;
    unsigned short* whi = (unsigned short*)(wsf + 6 * SZ + 50432);
    unsigned short* wlo = whi + W_TOTAL;
    unsigned short* wqkvc = wlo + W_TOTAL;   // compact [4][768][32] hi bf16
    float* bqkvp = (float*)(wqkvc + 98304);  // [4][768]

    pe_kernel<<<SEQ, 256, 0, stream>>>(peb);
    split_weights<<<768, 256, 0, stream>>>(w_map,  whi + W_MAP,  wlo + W_MAP,  196608);
    split_weights<<<1024, 256, 0, stream>>>(w_last, whi + W_LAST, wlo + W_LAST, 262144);
    split_weights<<<2048, 256, 0, stream>>>(w_mlp1, whi + W_MLP1, wlo + W_MLP1, 1048576);
    split_weights<<<2048, 256, 0, stream>>>(w_mlp2, whi + W_MLP2, wlo + W_MLP2, 1048576);
    pack_qkv_c<<<384, 256, 0, stream>>>(wq, wk, wv, wqkvc);
    pack_qkv_b<<<12, 256, 0, stream>>>(bq, bk, bv, bqkvp);

    embed_cls<<<NB, 256, 0, stream>>>(cls_tok, peb, outb);
    patch_mfma<<<dim3(196, 2), 256, 0, stream>>>(images, whi + W_MAP, wlo + W_MAP,
                                                 b_map, peb, outb);

    for (int l = 0; l < 4; ++l) {
        ln_kernel<<<MROWS, 256, 0, stream>>>(outb, xbuf, norm1_g + l * 256, norm1_b + l * 256);
        gemm_qkv<<<dim3(197, 6), 256, 0, stream>>>(
            xbuf, wqkvc + (size_t)l * 24576, bqkvp + l * 768, qkvb, MROWS, 768, 256);
        attn_mfma<<<NB * 8, 256, 0, stream>>>(qkvb, ob);
        gemm_mfma<0, true><<<dim3(197, 2), 256, 0, stream>>>(
            ob, whi + W_LAST + (size_t)l * 65536, wlo + W_LAST + (size_t)l * 65536,
            b_last + l * 256, outb, MROWS, 256, 256);
        ln_kernel<<<MROWS, 256, 0, stream>>>(outb, xbuf, norm2_g + l * 256, norm2_b + l * 256);
        gemm_mfma<1, false><<<dim3(197, 8), 256, 0, stream>>>(
            xbuf, whi + W_MLP1 + (size_t)l * 262144, wlo + W_MLP1 + (size_t)l * 262144,
            b_mlp1 + l * 1024, h1, MROWS, 1024, 256);
        gemm_mfma<0, true><<<dim3(197, 2), 256, 0, stream>>>(
            h1, whi + W_MLP2 + (size_t)l * 262144, wlo + W_MLP2 + (size_t)l * 262144,
            b_mlp2 + l * 256, outb, MROWS, 256, 1024);
    }
    head_kernel<<<NB, 256, 0, stream>>>(outb, w_out, b_out, (float*)d_out);
}

// Round 5
// 1392.209 us; speedup vs baseline: 3.0899x; 1.0359x over previous
//
#include <hip/hip_runtime.h>
#include <hip/hip_bf16.h>
#include <math.h>

// ---------------------------------------------------------------------------
// ViT forward. Round 4: pre-split bf16 activations + global_load_lds staging.
// B=128, C=3, 224x224, P=14, IN_D=768, D=256, H=8, DH=32, L=4, OUT=1000, S=197
// ---------------------------------------------------------------------------

#define SEQ 197
#define DIM 256
#define NB  128
#define MROWS (NB * SEQ)        // 25216 = 197*128

typedef __attribute__((ext_vector_type(4))) float f32x4;
typedef __attribute__((ext_vector_type(8))) __bf16 bf16x8;
typedef __attribute__((ext_vector_type(8))) short s16x8;

// async global->LDS, 16B per lane; LDS dest must be wave-uniform base
#define GLOAD16(g, l)                                                          \
    __builtin_amdgcn_global_load_lds(                                          \
        (const __attribute__((address_space(1))) void*)(g),                    \
        (__attribute__((address_space(3))) void*)(l), 16, 0, 0)

// round-to-nearest-even fp32 -> bf16 bits
__device__ __forceinline__ unsigned bf16_rn(float x) {
    union { float f; unsigned u; } c; c.f = x;
    return (c.u + 0x7fffu + ((c.u >> 16) & 1u)) >> 16;
}
__device__ __forceinline__ void split2(float a, unsigned short& hi, unsigned short& lo) {
    unsigned h = bf16_rn(a);
    hi = (unsigned short)h;
    union { unsigned u; float f; } hf; hf.u = h << 16;
    lo = (unsigned short)bf16_rn(a - hf.f);
}
// swizzled element offset in a [128 rows][32 k] ushort LDS tile (16B chunks XORed)
__device__ __forceinline__ int swz(int row, int c) {
    return row * 32 + ((c ^ ((row >> 1) & 3)) << 3);
}

// ---------------------------------------------------------------------------
__global__ __launch_bounds__(256) void pe_kernel(float* __restrict__ pe) {
    int s = blockIdx.x, j = threadIdx.x;
    int jh = j >> 1;
    float expo = (float)(2 * jh) * (1.0f / 256.0f);
    float inv_freq = exp2f(-expo * 13.287712379549449f);
    float angle = (float)s * inv_freq;
    pe[s * 256 + j] = (j & 1) ? cosf(angle) : sinf(angle);
}

__global__ __launch_bounds__(256) void embed_cls(const float* __restrict__ cls_tok,
                                                 const float* __restrict__ pe,
                                                 float* __restrict__ out) {
    int n = blockIdx.x, d = threadIdx.x;
    out[(size_t)n * SEQ * DIM + d] = cls_tok[d] + pe[d];
}

// split fp32 weights into hi/lo bf16 copies
__global__ __launch_bounds__(256) void split_weights(const float* __restrict__ src,
                                                     unsigned short* __restrict__ hi,
                                                     unsigned short* __restrict__ lo, int n) {
    for (int i = blockIdx.x * 256 + threadIdx.x; i < n; i += gridDim.x * 256) {
        unsigned short h, l;
        split2(src[i], h, l);
        hi[i] = h; lo[i] = l;
    }
}

// Compact QKV weights: wc[l][j][d] (j = m*256 + hh*32 + e, d = 0..31), hi bf16.
__global__ __launch_bounds__(256) void pack_qkv_c(const float* __restrict__ wq,
                                                  const float* __restrict__ wk,
                                                  const float* __restrict__ wv,
                                                  unsigned short* __restrict__ wc) {
    int e = blockIdx.x * 256 + threadIdx.x;     // < 4*768*32 = 98304
    if (e >= 98304) return;
    int l = e / 24576, r = e % 24576;
    int j = r >> 5, d = r & 31;
    int m = j >> 8, hh = (j >> 5) & 7, ee = j & 31;
    const float* w = (m == 0) ? wq : (m == 1) ? wk : wv;
    wc[e] = (unsigned short)bf16_rn(w[(((size_t)l * 8 + hh) * 32 + ee) * 32 + d]);
}

__global__ __launch_bounds__(256) void pack_qkv_b(const float* __restrict__ bq,
                                                  const float* __restrict__ bk,
                                                  const float* __restrict__ bv,
                                                  float* __restrict__ bp) {
    int e = blockIdx.x * 256 + threadIdx.x;     // < 4*768 = 3072
    if (e >= 3072) return;
    int l = e / 768, j = e % 768;
    int m = j >> 8, jj = j & 255;
    const float* b = (m == 0) ? bq : (m == 1) ? bk : bv;
    bp[e] = b[l * 256 + jj];
}

// ---------------------------------------------------------------------------
// GEMM with pre-split bf16 A and B, async LDS staging.
// C[M,N] = act(A * B^T + bias);  OMODE: 0 store f32, 1 accum f32,
// 2 split hi/lo bf16 write, 3 hi-only bf16 write. ALO: A has lo part.
template <int ACT, int OMODE, bool ALO>
__global__ __launch_bounds__(256) void gemm_as(const unsigned short* __restrict__ Ahi,
                                               const unsigned short* __restrict__ Alo,
                                               const unsigned short* __restrict__ Bhi,
                                               const unsigned short* __restrict__ Blo,
                                               const float* __restrict__ bias,
                                               float* __restrict__ C,
                                               unsigned short* __restrict__ Chi,
                                               unsigned short* __restrict__ Clo,
                                               int M, int N, int K) {
    __shared__ unsigned short Ah[4096], Al[4096], Bh[4096], Bl[4096];
    const int tid = threadIdx.x;
    const int bm = blockIdx.y * 128, bn = blockIdx.x * 128;
    const int lane = tid & 63, wid = tid >> 6;
    const int wm = wid & 1, wn = wid >> 1;
    const int q = lane >> 4, r15 = lane & 15;
    const int rl = lane >> 2, cc = lane & 3;
    const int wr = wid * 32;

    // staging source pointers: lane covers (row, chunk); source chunk is
    // pre-swizzled so the linear LDS write reproduces the swizzled layout.
    const int row0 = wr + rl, row1 = wr + 16 + rl;
    const int cx0 = (cc ^ ((row0 >> 1) & 3)) << 3;
    const int cx1 = (cc ^ ((row1 >> 1) & 3)) << 3;
    const unsigned short* ah0 = Ahi + (size_t)(bm + row0) * K + cx0;
    const unsigned short* ah1 = Ahi + (size_t)(bm + row1) * K + cx1;
    const unsigned short* al0 = Alo + (size_t)(bm + row0) * K + cx0;
    const unsigned short* al1 = Alo + (size_t)(bm + row1) * K + cx1;
    const unsigned short* bh0 = Bhi + (size_t)(bn + row0) * K + cx0;
    const unsigned short* bh1 = Bhi + (size_t)(bn + row1) * K + cx1;
    const unsigned short* bl0 = Blo + (size_t)(bn + row0) * K + cx0;
    const unsigned short* bl1 = Blo + (size_t)(bn + row1) * K + cx1;

    f32x4 acc[4][4];
#pragma unroll
    for (int i = 0; i < 4; ++i)
#pragma unroll
        for (int j = 0; j < 4; ++j) acc[i][j] = (f32x4){0.f, 0.f, 0.f, 0.f};

    for (int k0 = 0; k0 < K; k0 += 32) {
        GLOAD16(ah0 + k0, &Ah[wr * 32]);
        GLOAD16(ah1 + k0, &Ah[(wr + 16) * 32]);
        if constexpr (ALO) {
            GLOAD16(al0 + k0, &Al[wr * 32]);
            GLOAD16(al1 + k0, &Al[(wr + 16) * 32]);
        }
        GLOAD16(bh0 + k0, &Bh[wr * 32]);
        GLOAD16(bh1 + k0, &Bh[(wr + 16) * 32]);
        GLOAD16(bl0 + k0, &Bl[wr * 32]);
        GLOAD16(bl1 + k0, &Bl[(wr + 16) * 32]);
        __syncthreads();

        s16x8 ah[4], al[4], bhf[4], blf[4];
#pragma unroll
        for (int m = 0; m < 4; ++m) {
            int row = wm * 64 + m * 16 + r15;
            int off = row * 32 + ((q ^ ((row >> 1) & 3)) << 3);
            ah[m] = *(const s16x8*)&Ah[off];
            if constexpr (ALO) al[m] = *(const s16x8*)&Al[off];
        }
#pragma unroll
        for (int n = 0; n < 4; ++n) {
            int row = wn * 64 + n * 16 + r15;
            int off = row * 32 + ((q ^ ((row >> 1) & 3)) << 3);
            bhf[n] = *(const s16x8*)&Bh[off];
            blf[n] = *(const s16x8*)&Bl[off];
        }
#pragma unroll
        for (int m = 0; m < 4; ++m)
#pragma unroll
            for (int n = 0; n < 4; ++n) {
                bf16x8 a_h = __builtin_bit_cast(bf16x8, ah[m]);
                bf16x8 b_h = __builtin_bit_cast(bf16x8, bhf[n]);
                bf16x8 b_l = __builtin_bit_cast(bf16x8, blf[n]);
                acc[m][n] = __builtin_amdgcn_mfma_f32_16x16x32_bf16(a_h, b_h, acc[m][n], 0, 0, 0);
                acc[m][n] = __builtin_amdgcn_mfma_f32_16x16x32_bf16(a_h, b_l, acc[m][n], 0, 0, 0);
                if constexpr (ALO) {
                    bf16x8 a_l = __builtin_bit_cast(bf16x8, al[m]);
                    acc[m][n] = __builtin_amdgcn_mfma_f32_16x16x32_bf16(a_l, b_h, acc[m][n], 0, 0, 0);
                }
            }
        __syncthreads();
    }

#pragma unroll
    for (int n = 0; n < 4; ++n) {
        int col = bn + wn * 64 + n * 16 + r15;
        float bb = bias[col];
#pragma unroll
        for (int m = 0; m < 4; ++m) {
            int r0 = bm + wm * 64 + m * 16 + q * 4;
#pragma unroll
            for (int i = 0; i < 4; ++i) {
                float v = acc[m][n][i] + bb;
                if (ACT == 1) v = 0.5f * v * (1.0f + erff(v * 0.70710678118654752f));
                size_t off = (size_t)(r0 + i) * N + col;
                if constexpr (OMODE == 0) C[off] = v;
                else if constexpr (OMODE == 1) C[off] += v;
                else if constexpr (OMODE == 2) {
                    unsigned short hh, ll; split2(v, hh, ll);
                    Chi[off] = hh; Clo[off] = ll;
                } else {
                    Chi[off] = (unsigned short)bf16_rn(v);
                }
            }
        }
    }
}

// ---------------------------------------------------------------------------
// QKV GEMM: A pre-split (gload), COMPACT block-diagonal B (hi only, reg-staged),
// split bf16 output. M=MROWS, N=768, K=256.
__global__ __launch_bounds__(256) void gemm_qkv2(const unsigned short* __restrict__ Ahi,
                                                 const unsigned short* __restrict__ Alo,
                                                 const unsigned short* __restrict__ Bc,
                                                 const float* __restrict__ bias,
                                                 unsigned short* __restrict__ Chi,
                                                 unsigned short* __restrict__ Clo) {
    __shared__ unsigned short Ah[4096], Al[4096], Bh[4096];
    const int tid = threadIdx.x;
    const int bm = blockIdx.y * 128, bn = blockIdx.x * 128;
    const int lane = tid & 63, wid = tid >> 6;
    const int wm = wid & 1, wn = wid >> 1;
    const int q = lane >> 4, r15 = lane & 15;
    const int rl = lane >> 2, cc = lane & 3;
    const int wr = wid * 32;
    const int K = 256, N = 768;

    const int row0 = wr + rl, row1 = wr + 16 + rl;
    const int cx0 = (cc ^ ((row0 >> 1) & 3)) << 3;
    const int cx1 = (cc ^ ((row1 >> 1) & 3)) << 3;
    const unsigned short* ah0 = Ahi + (size_t)(bm + row0) * K + cx0;
    const unsigned short* ah1 = Ahi + (size_t)(bm + row1) * K + cx1;
    const unsigned short* al0 = Alo + (size_t)(bm + row0) * K + cx0;
    const unsigned short* al1 = Alo + (size_t)(bm + row1) * K + cx1;

    const int srow = tid >> 2, sc = tid & 3;
    const int j0 = bn + srow, j1 = bn + srow + 64;
    const int c0 = (j0 >> 5) & 7, c1 = (j1 >> 5) & 7;
    const unsigned short* bc0 = Bc + (size_t)j0 * 32 + sc * 8;
    const unsigned short* bc1 = Bc + (size_t)j1 * 32 + sc * 8;
    const int soff0 = swz(srow, sc), soff1 = swz(srow + 64, sc);

    f32x4 acc[4][4];
#pragma unroll
    for (int i = 0; i < 4; ++i)
#pragma unroll
        for (int j = 0; j < 4; ++j) acc[i][j] = (f32x4){0.f, 0.f, 0.f, 0.f};

    const s16x8 bz = (s16x8){0, 0, 0, 0, 0, 0, 0, 0};
    for (int k0 = 0; k0 < K; k0 += 32) {
        const int kc = k0 >> 5;
        GLOAD16(ah0 + k0, &Ah[wr * 32]);
        GLOAD16(ah1 + k0, &Ah[(wr + 16) * 32]);
        GLOAD16(al0 + k0, &Al[wr * 32]);
        GLOAD16(al1 + k0, &Al[(wr + 16) * 32]);
        *(s16x8*)&Bh[soff0] = (c0 == kc) ? *(const s16x8*)bc0 : bz;
        *(s16x8*)&Bh[soff1] = (c1 == kc) ? *(const s16x8*)bc1 : bz;
        __syncthreads();

        s16x8 ah[4], al[4], bhf[4];
#pragma unroll
        for (int m = 0; m < 4; ++m) {
            int row = wm * 64 + m * 16 + r15;
            int off = row * 32 + ((q ^ ((row >> 1) & 3)) << 3);
            ah[m] = *(const s16x8*)&Ah[off];
            al[m] = *(const s16x8*)&Al[off];
        }
#pragma unroll
        for (int n = 0; n < 4; ++n) {
            int row = wn * 64 + n * 16 + r15;
            int off = row * 32 + ((q ^ ((row >> 1) & 3)) << 3);
            bhf[n] = *(const s16x8*)&Bh[off];
        }
#pragma unroll
        for (int m = 0; m < 4; ++m)
#pragma unroll
            for (int n = 0; n < 4; ++n) {
                bf16x8 a_h = __builtin_bit_cast(bf16x8, ah[m]);
                bf16x8 a_l = __builtin_bit_cast(bf16x8, al[m]);
                bf16x8 b_h = __builtin_bit_cast(bf16x8, bhf[n]);
                acc[m][n] = __builtin_amdgcn_mfma_f32_16x16x32_bf16(a_h, b_h, acc[m][n], 0, 0, 0);
                acc[m][n] = __builtin_amdgcn_mfma_f32_16x16x32_bf16(a_l, b_h, acc[m][n], 0, 0, 0);
            }
        __syncthreads();
    }

#pragma unroll
    for (int n = 0; n < 4; ++n) {
        int col = bn + wn * 64 + n * 16 + r15;
        float bb = bias[col];
#pragma unroll
        for (int m = 0; m < 4; ++m) {
            int r0 = bm + wm * 64 + m * 16 + q * 4;
#pragma unroll
            for (int i = 0; i < 4; ++i) {
                float v = acc[m][n][i] + bb;
                size_t off = (size_t)(r0 + i) * N + col;
                unsigned short hh, ll; split2(v, hh, ll);
                Chi[off] = hh; Clo[off] = ll;
            }
        }
    }
}

// ---------------------------------------------------------------------------
// Patch-embed GEMM (reg-staged, one-time). M=25088, N=256, K=768.
__global__ __launch_bounds__(256) void patch_mfma(const float* __restrict__ images,
                                                  const unsigned short* __restrict__ Bhi,
                                                  const unsigned short* __restrict__ Blo,
                                                  const float* __restrict__ b_map,
                                                  const float* __restrict__ pe,
                                                  float* __restrict__ out) {
    __shared__ unsigned short Ah[4096], Al[4096], Bh[4096], Bl[4096];
    const int tid = threadIdx.x;
    const int bm = blockIdx.y * 128, bn = blockIdx.x * 128;
    const int lane = tid & 63, wid = tid >> 6;
    const int wm = wid & 1, wn = wid >> 1;
    const int q = lane >> 4, r15 = lane & 15;
    const int srow = tid >> 2, sc = tid & 3;

    const float* ibase[2];
    {
        int rows[2] = {bm + srow, bm + srow + 64};
#pragma unroll
        for (int t = 0; t < 2; ++t) {
            int n = rows[t] / 196, p = rows[t] % 196;
            ibase[t] = images + (size_t)n * 150528 + (size_t)(p / 14) * 3584 + (p % 14) * 16;
        }
    }
    const int soff0 = swz(srow, sc), soff1 = swz(srow + 64, sc);
    const unsigned short* bh0 = Bhi + (size_t)(bn + srow) * 768 + sc * 8;
    const unsigned short* bl0 = Blo + (size_t)(bn + srow) * 768 + sc * 8;
    const unsigned short* bh1 = Bhi + (size_t)(bn + srow + 64) * 768 + sc * 8;
    const unsigned short* bl1 = Blo + (size_t)(bn + srow + 64) * 768 + sc * 8;

    f32x4 acc[4][4];
#pragma unroll
    for (int i = 0; i < 4; ++i)
#pragma unroll
        for (int j = 0; j < 4; ++j) acc[i][j] = (f32x4){0.f, 0.f, 0.f, 0.f};

    for (int k0 = 0; k0 < 768; k0 += 32) {
        int k = k0 + sc * 8;
        int aoff = (k >> 8) * 50176 + (((k >> 4) & 15)) * 224 + (k & 15);
        {
            float4 v0 = *(const float4*)(ibase[0] + aoff);
            float4 v1 = *(const float4*)(ibase[0] + aoff + 4);
            float vv[8] = {v0.x, v0.y, v0.z, v0.w, v1.x, v1.y, v1.z, v1.w};
            s16x8 hv, lv;
#pragma unroll
            for (int j = 0; j < 8; ++j) {
                unsigned short h, l; split2(vv[j], h, l);
                hv[j] = (short)h; lv[j] = (short)l;
            }
            *(s16x8*)&Ah[soff0] = hv; *(s16x8*)&Al[soff0] = lv;
            v0 = *(const float4*)(ibase[1] + aoff);
            v1 = *(const float4*)(ibase[1] + aoff + 4);
            float ww[8] = {v0.x, v0.y, v0.z, v0.w, v1.x, v1.y, v1.z, v1.w};
#pragma unroll
            for (int j = 0; j < 8; ++j) {
                unsigned short h, l; split2(ww[j], h, l);
                hv[j] = (short)h; lv[j] = (short)l;
            }
            *(s16x8*)&Ah[soff1] = hv; *(s16x8*)&Al[soff1] = lv;
        }
        *(s16x8*)&Bh[soff0] = *(const s16x8*)(bh0 + k0);
        *(s16x8*)&Bl[soff0] = *(const s16x8*)(bl0 + k0);
        *(s16x8*)&Bh[soff1] = *(const s16x8*)(bh1 + k0);
        *(s16x8*)&Bl[soff1] = *(const s16x8*)(bl1 + k0);
        __syncthreads();

        s16x8 ah[4], al[4], bhf[4], blf[4];
#pragma unroll
        for (int m = 0; m < 4; ++m) {
            int row = wm * 64 + m * 16 + r15;
            int off = row * 32 + ((q ^ ((row >> 1) & 3)) << 3);
            ah[m] = *(const s16x8*)&Ah[off];
            al[m] = *(const s16x8*)&Al[off];
        }
#pragma unroll
        for (int n = 0; n < 4; ++n) {
            int row = wn * 64 + n * 16 + r15;
            int off = row * 32 + ((q ^ ((row >> 1) & 3)) << 3);
            bhf[n] = *(const s16x8*)&Bh[off];
            blf[n] = *(const s16x8*)&Bl[off];
        }
#pragma unroll
        for (int m = 0; m < 4; ++m)
#pragma unroll
            for (int n = 0; n < 4; ++n) {
                bf16x8 a_h = __builtin_bit_cast(bf16x8, ah[m]);
                bf16x8 a_l = __builtin_bit_cast(bf16x8, al[m]);
                bf16x8 b_h = __builtin_bit_cast(bf16x8, bhf[n]);
                bf16x8 b_l = __builtin_bit_cast(bf16x8, blf[n]);
                acc[m][n] = __builtin_amdgcn_mfma_f32_16x16x32_bf16(a_h, b_h, acc[m][n], 0, 0, 0);
                acc[m][n] = __builtin_amdgcn_mfma_f32_16x16x32_bf16(a_h, b_l, acc[m][n], 0, 0, 0);
                acc[m][n] = __builtin_amdgcn_mfma_f32_16x16x32_bf16(a_l, b_h, acc[m][n], 0, 0, 0);
            }
        __syncthreads();
    }

#pragma unroll
    for (int n = 0; n < 4; ++n) {
        int col = bn + wn * 64 + n * 16 + r15;
        float bb = b_map[col];
#pragma unroll
        for (int m = 0; m < 4; ++m) {
            int row0 = bm + wm * 64 + m * 16 + q * 4;
#pragma unroll
            for (int i = 0; i < 4; ++i) {
                int rowg = row0 + i;
                int n_img = rowg / 196;
                int p = rowg - n_img * 196;
                out[((size_t)n_img * SEQ + 1 + p) * DIM + col] =
                    acc[m][n][i] + bb + pe[(1 + p) * DIM + col];
            }
        }
    }
}

// ---------------------------------------------------------------------------
// MFMA attention reading pre-split qkv; writes split bf16 O.
__global__ __launch_bounds__(256) void attn_mfma2(const unsigned short* __restrict__ qkvh,
                                                  const unsigned short* __restrict__ qkvl,
                                                  unsigned short* __restrict__ oh,
                                                  unsigned short* __restrict__ ol) {
    __shared__ unsigned short Kh[208 * 40];      // K[s][d], rows >=197 zero
    __shared__ unsigned short Vt[32 * 232];      // V^T[d][t], cols >=197 zero
    __shared__ unsigned short Pb[4][16 * 232];   // per-wave P[qr][t]
    const int tid = threadIdx.x;
    const int lane = tid & 63, wid = tid >> 6;
    const int qh = lane >> 4, qr = lane & 15;
    const int n = blockIdx.x >> 3, h = blockIdx.x & 7;
    const size_t rowbase = (size_t)n * SEQ;
    const float scale = 0.17677669529663687f;    // 1/sqrt(32)

    for (int i = tid; i < 208 * 40 / 2; i += 256) ((uint32_t*)Kh)[i] = 0;
    for (int i = tid; i < 32 * 232 / 2; i += 256) ((uint32_t*)Vt)[i] = 0;
    for (int i = tid; i < 4 * 16 * 232 / 2; i += 256) ((uint32_t*)&Pb[0][0])[i] = 0;
    __syncthreads();

    // stage K (hi) vectorized and V^T (hi) transposed
    for (int e = tid; e < SEQ * 4; e += 256) {
        int s = e >> 2, c = e & 3;
        *(s16x8*)&Kh[s * 40 + c * 8] =
            *(const s16x8*)(qkvh + (rowbase + s) * 768 + 256 + h * 32 + c * 8);
    }
    for (int e = tid; e < SEQ * 32; e += 256) {
        int s = e >> 5, d = e & 31;
        Vt[d * 232 + s] = qkvh[(rowbase + s) * 768 + 512 + h * 32 + d];
    }
    __syncthreads();

    unsigned short* Pw = Pb[wid];
    for (int st = wid; st < 13; st += 4) {
        int srow = st * 16 + qr; if (srow > SEQ - 1) srow = SEQ - 1;
        const size_t qoff = (rowbase + srow) * 768 + h * 32 + qh * 8;
        bf16x8 qH = *(const bf16x8*)(qkvh + qoff);
        bf16x8 qL = *(const bf16x8*)(qkvl + qoff);

        // S^T: sacc[tt][i] = S_raw[t = 16tt+4qh+i][qrow]
        f32x4 sacc[13];
#pragma unroll
        for (int tt = 0; tt < 13; ++tt) sacc[tt] = (f32x4){0.f, 0.f, 0.f, 0.f};
#pragma unroll
        for (int tt = 0; tt < 13; ++tt) {
            bf16x8 kf = *(const bf16x8*)&Kh[(tt * 16 + qr) * 40 + qh * 8];
            sacc[tt] = __builtin_amdgcn_mfma_f32_16x16x32_bf16(kf, qH, sacc[tt], 0, 0, 0);
            sacc[tt] = __builtin_amdgcn_mfma_f32_16x16x32_bf16(kf, qL, sacc[tt], 0, 0, 0);
        }
        // mask invalid t (raw units; real |S_raw| << 1e4)
#pragma unroll
        for (int i = 0; i < 4; ++i)
            if (192 + 4 * qh + i > SEQ - 1) sacc[12][i] = -1e4f;
        float mx = -1e4f;
#pragma unroll
        for (int tt = 0; tt < 13; ++tt)
#pragma unroll
            for (int i = 0; i < 4; ++i) mx = fmaxf(mx, sacc[tt][i]);
        mx = fmaxf(mx, __shfl_xor(mx, 16, 64));
        mx = fmaxf(mx, __shfl_xor(mx, 32, 64));
        float sum = 0.f;
#pragma unroll
        for (int tt = 0; tt < 13; ++tt)
#pragma unroll
            for (int i = 0; i < 4; ++i) {
                float p = __expf((sacc[tt][i] - mx) * scale);
                sacc[tt][i] = p; sum += p;
            }
        sum += __shfl_xor(sum, 16, 64);
        sum += __shfl_xor(sum, 32, 64);
        float inv = 1.0f / sum;
#pragma unroll
        for (int tt = 0; tt < 13; ++tt)
#pragma unroll
            for (int i = 0; i < 4; ++i)
                Pw[qr * 232 + tt * 16 + 4 * qh + i] = (unsigned short)bf16_rn(sacc[tt][i]);
#pragma unroll
        for (int i = 0; i < 4; ++i)
            Pw[qr * 232 + 208 + 4 * qh + i] = 0;

        // O^T = V^T * P^T
        f32x4 oacc[2];
        oacc[0] = (f32x4){0.f, 0.f, 0.f, 0.f};
        oacc[1] = (f32x4){0.f, 0.f, 0.f, 0.f};
#pragma unroll
        for (int kt = 0; kt < 7; ++kt) {
            bf16x8 pf = *(const bf16x8*)&Pw[qr * 232 + kt * 32 + qh * 8];
            bf16x8 v0 = *(const bf16x8*)&Vt[qr * 232 + kt * 32 + qh * 8];
            bf16x8 v1 = *(const bf16x8*)&Vt[(16 + qr) * 232 + kt * 32 + qh * 8];
            oacc[0] = __builtin_amdgcn_mfma_f32_16x16x32_bf16(v0, pf, oacc[0], 0, 0, 0);
            oacc[1] = __builtin_amdgcn_mfma_f32_16x16x32_bf16(v1, pf, oacc[1], 0, 0, 0);
        }
        if (st * 16 + qr < SEQ) {
            size_t obase = (rowbase + st * 16 + qr) * DIM + h * 32;
#pragma unroll
            for (int dt = 0; dt < 2; ++dt)
#pragma unroll
                for (int i = 0; i < 4; ++i) {
                    unsigned short hh, ll;
                    split2(oacc[dt][i] * inv, hh, ll);
                    oh[obase + dt * 16 + 4 * qh + i] = hh;
                    ol[obase + dt * 16 + 4 * qh + i] = ll;
                }
        }
    }
}

// ---------------------------------------------------------------------------
// LayerNorm -> split bf16 output. One block per row.
__global__ __launch_bounds__(256) void ln_split(const float* __restrict__ x,
                                                unsigned short* __restrict__ yh,
                                                unsigned short* __restrict__ yl,
                                                const float* __restrict__ g,
                                                const float* __restrict__ b) {
    int row = blockIdx.x, tid = threadIdx.x;
    float v = x[(size_t)row * DIM + tid];
    float s = v;
#pragma unroll
    for (int off = 32; off; off >>= 1) s += __shfl_down(s, off, 64);
    __shared__ float red[4];
    if ((tid & 63) == 0) red[tid >> 6] = s;
    __syncthreads();
    float mu = (red[0] + red[1] + red[2] + red[3]) * (1.0f / 256.0f);
    float d = v - mu;
    float s2 = d * d;
#pragma unroll
    for (int off = 32; off; off >>= 1) s2 += __shfl_down(s2, off, 64);
    __shared__ float red2[4];
    if ((tid & 63) == 0) red2[tid >> 6] = s2;
    __syncthreads();
    float var = (red2[0] + red2[1] + red2[2] + red2[3]) * (1.0f / 256.0f);
    float inv_std = 1.0f / sqrtf(var + 1e-5f);
    float y = d * inv_std * g[tid] + b[tid];
    unsigned short hh, ll; split2(y, hh, ll);
    size_t off = (size_t)row * DIM + tid;
    yh[off] = hh; yl[off] = ll;
}

// ---------------------------------------------------------------------------
__global__ __launch_bounds__(256) void head_kernel(const float* __restrict__ xin,
                                                   const float* __restrict__ w,
                                                   const float* __restrict__ bias,
                                                   float* __restrict__ res) {
    int n = blockIdx.x, tid = threadIdx.x;
    __shared__ float xs[256];
    xs[tid] = xin[(size_t)n * SEQ * DIM + tid];
    __syncthreads();
    float lg[4];
#pragma unroll
    for (int u = 0; u < 4; ++u) {
        int j = u * 256 + tid;
        float acc = -1e30f;
        if (j < 1000) {
            acc = bias[j];
            for (int kk = 0; kk < 256; kk += 4) {
                float4 wv = *reinterpret_cast<const float4*>(&w[(size_t)j * 256 + kk]);
                acc += xs[kk] * wv.x + xs[kk + 1] * wv.y + xs[kk + 2] * wv.z + xs[kk + 3] * wv.w;
            }
        }
        lg[u] = acc;
    }
    float mx = fmaxf(fmaxf(lg[0], lg[1]), fmaxf(lg[2], lg[3]));
#pragma unroll
    for (int off = 32; off; off >>= 1) mx = fmaxf(mx, __shfl_down(mx, off, 64));
    __shared__ float redm[4];
    if ((tid & 63) == 0) redm[tid >> 6] = mx;
    __syncthreads();
    mx = fmaxf(fmaxf(redm[0], redm[1]), fmaxf(redm[2], redm[3]));
    float e[4], ssum = 0.f;
#pragma unroll
    for (int u = 0; u < 4; ++u) {
        int j = u * 256 + tid;
        e[u] = (j < 1000) ? expf(lg[u] - mx) : 0.f;
        ssum += e[u];
    }
#pragma unroll
    for (int off = 32; off; off >>= 1) ssum += __shfl_down(ssum, off, 64);
    __shared__ float reds[4];
    if ((tid & 63) == 0) reds[tid >> 6] = ssum;
    __syncthreads();
    float inv = 1.0f / (reds[0] + reds[1] + reds[2] + reds[3]);
#pragma unroll
    for (int u = 0; u < 4; ++u) {
        int j = u * 256 + tid;
        if (j < 1000) res[(size_t)n * 1000 + j] = e[u] * inv;
    }
}

// ---------------------------------------------------------------------------
extern "C" void kernel_launch(void* const* d_in, const int* in_sizes, int n_in,
                              void* d_out, int out_size, void* d_ws, size_t ws_size,
                              hipStream_t stream) {
    const float* images  = (const float*)d_in[0];
    const float* w_map   = (const float*)d_in[1];
    const float* b_map   = (const float*)d_in[2];
    const float* cls_tok = (const float*)d_in[3];
    const float* norm1_g = (const float*)d_in[4];
    const float* norm1_b = (const float*)d_in[5];
    const float* wq      = (const float*)d_in[6];
    const float* bq      = (const float*)d_in[7];
    const float* wk      = (const float*)d_in[8];
    const float* bk      = (const float*)d_in[9];
    const float* wv      = (const float*)d_in[10];
    const float* bv      = (const float*)d_in[11];
    const float* w_last  = (const float*)d_in[12];
    const float* b_last  = (const float*)d_in[13];
    const float* norm2_g = (const float*)d_in[14];
    const float* norm2_b = (const float*)d_in[15];
    const float* w_mlp1  = (const float*)d_in[16];
    const float* b_mlp1  = (const float*)d_in[17];
    const float* w_mlp2  = (const float*)d_in[18];
    const float* b_mlp2  = (const float*)d_in[19];
    const float* w_out   = (const float*)d_in[20];
    const float* b_out   = (const float*)d_in[21];

    float* wsf = (float*)d_ws;
    const size_t SZ = (size_t)MROWS * DIM;   // 6,455,296 floats
    float* outb = wsf;                               // residual [M,256] f32
    unsigned short* xh  = (unsigned short*)(wsf + SZ);       // LN out hi
    unsigned short* xl  = xh + SZ;                           // LN out lo
    unsigned short* qkvh = (unsigned short*)(wsf + 2 * SZ);  // [M,768] hi
    unsigned short* qkvl = qkvh + 3 * SZ;                    // [M,768] lo
    unsigned short* h1h = (unsigned short*)(wsf + 2 * SZ);   // [M,1024] hi (aliases dead qkv)
    unsigned short* oh  = (unsigned short*)(wsf + 5 * SZ);   // attn out hi
    unsigned short* olo = oh + SZ;                           // attn out lo
    float* peb  = wsf + 6 * SZ;                              // 50432 floats

    // weight buffers: identical layout to R3 (proven within ws_size)
    const size_t W_MAP  = 0;                 // 196608
    const size_t W_LAST = 196608;            // 4 * 65536
    const size_t W_MLP1 = 458752;            // 4 * 262144
    const size_t W_MLP2 = 1507328;           // 4 * 262144
    const size_t W_TOTAL = 2555904;
    unsigned short* whi = (unsigned short*)(wsf + 6 * SZ + 50432);
    unsigned short* wlo = whi + W_TOTAL;
    unsigned short* wqkvc = wlo + W_TOTAL;   // compact [4][768][32] hi bf16
    float* bqkvp = (float*)(wqkvc + 98304);  // [4][768]

    pe_kernel<<<SEQ, 256, 0, stream>>>(peb);
    split_weights<<<768, 256, 0, stream>>>(w_map,  whi + W_MAP,  wlo + W_MAP,  196608);
    split_weights<<<1024, 256, 0, stream>>>(w_last, whi + W_LAST, wlo + W_LAST, 262144);
    split_weights<<<2048, 256, 0, stream>>>(w_mlp1, whi + W_MLP1, wlo + W_MLP1, 1048576);
    split_weights<<<2048, 256, 0, stream>>>(w_mlp2, whi + W_MLP2, wlo + W_MLP2, 1048576);
    pack_qkv_c<<<384, 256, 0, stream>>>(wq, wk, wv, wqkvc);
    pack_qkv_b<<<12, 256, 0, stream>>>(bq, bk, bv, bqkvp);

    embed_cls<<<NB, 256, 0, stream>>>(cls_tok, peb, outb);
    patch_mfma<<<dim3(2, 196), 256, 0, stream>>>(images, whi + W_MAP, wlo + W_MAP,
                                                 b_map, peb, outb);

    for (int l = 0; l < 4; ++l) {
        ln_split<<<MROWS, 256, 0, stream>>>(outb, xh, xl, norm1_g + l * 256, norm1_b + l * 256);
        gemm_qkv2<<<dim3(6, 197), 256, 0, stream>>>(
            xh, xl, wqkvc + (size_t)l * 24576, bqkvp + l * 768, qkvh, qkvl);
        attn_mfma2<<<NB * 8, 256, 0, stream>>>(qkvh, qkvl, oh, olo);
        gemm_as<0, 1, true><<<dim3(2, 197), 256, 0, stream>>>(
            oh, olo, whi + W_LAST + (size_t)l * 65536, wlo + W_LAST + (size_t)l * 65536,
            b_last + l * 256, outb, oh, olo, MROWS, 256, 256);
        ln_split<<<MROWS, 256, 0, stream>>>(outb, xh, xl, norm2_g + l * 256, norm2_b + l * 256);
        gemm_as<1, 3, true><<<dim3(8, 197), 256, 0, stream>>>(
            xh, xl, whi + W_MLP1 + (size_t)l * 262144, wlo + W_MLP1 + (size_t)l * 262144,
            b_mlp1 + l * 1024, outb, h1h, h1h, MROWS, 1024, 256);
        gemm_as<0, 1, false><<<dim3(2, 197), 256, 0, stream>>>(
            h1h, h1h, whi + W_MLP2 + (size_t)l * 262144, wlo + W_MLP2 + (size_t)l * 262144,
            b_mlp2 + l * 256, outb, oh, olo, MROWS, 256, 1024);
    }
    head_kernel<<<NB, 256, 0, stream>>>(outb, w_out, b_out, (float*)d_out);
}